// Round 7
// baseline (901.086 us; speedup 1.0000x reference)
//
#include <hip/hip_runtime.h>
#include <hip/hip_bf16.h>
#include <math.h>

#define NU 50000
#define NFOOD 30000
#define NING 20000
#define NCAT 5000
#define NHAB 10000
#define NNODES 115000
#define NREL 8
#define NEDGE 1500000
#define SCAN_B 256

typedef __attribute__((ext_vector_type(8))) short short8;
typedef __attribute__((ext_vector_type(4))) float f32x4;

static inline size_t alignup(size_t x) { return (x + 255) & ~(size_t)255; }

__device__ inline float bf16_bits_to_f32(unsigned short u) {
  return __uint_as_float(((unsigned)u) << 16);
}
__device__ inline unsigned short f32_to_bf16_bits(float f) {
  unsigned u = __float_as_uint(f);
  unsigned r = u + 0x7fffu + ((u >> 16) & 1u);
  return (unsigned short)(r >> 16);
}

// ================= MFMA bf16 GEMM (projections + layer-2) ==========================
// C[M,N] = op(A)[M,K] @ B_T[N,K] (+bias).  A row-major, lda==K. Bt [N][ldB] bf16.
// Tile 128x128, BK=64, 256 thr = 4 waves. LDS XOR swizzle byte ^= (row&7)<<4.
template <bool A_F32, bool OUT_BF16>
__global__ __launch_bounds__(256) void mfma_gemm(
    const void* __restrict__ Ain, const unsigned short* __restrict__ Bt, int ldB,
    const float* __restrict__ bias, void* __restrict__ Cv, int ldC, int Nstore,
    int M, int N, int K) {
  __shared__ char As[128 * 128];
  __shared__ char Bs[128 * 128];
  const int tid = threadIdx.x;
  const int lane = tid & 63;
  const int wv = tid >> 6;
  const int bm = blockIdx.y * 128;
  const int bn = blockIdx.x * 128;
  f32x4 acc[2][8] = {};

  for (int k0 = 0; k0 < K; k0 += 64) {
    if (A_F32) {
      const float* A = (const float*)Ain;
#pragma unroll
      for (int it = 0; it < 4; ++it) {
        int u = it * 256 + tid;
        int m = u >> 3, c = u & 7;
        int mg = bm + m; if (mg >= M) mg = M - 1;
        const float4* src = (const float4*)(A + (size_t)mg * K + k0 + c * 8);
        float4 lo4 = src[0], hi4 = src[1];
        unsigned q0 = f32_to_bf16_bits(lo4.x) | ((unsigned)f32_to_bf16_bits(lo4.y) << 16);
        unsigned q1 = f32_to_bf16_bits(lo4.z) | ((unsigned)f32_to_bf16_bits(lo4.w) << 16);
        unsigned q2 = f32_to_bf16_bits(hi4.x) | ((unsigned)f32_to_bf16_bits(hi4.y) << 16);
        unsigned q3 = f32_to_bf16_bits(hi4.z) | ((unsigned)f32_to_bf16_bits(hi4.w) << 16);
        int off = m * 128 + ((c * 16) ^ ((m & 7) << 4));
        *(int4*)(As + off) = make_int4(q0, q1, q2, q3);
      }
    } else {
      const unsigned short* A = (const unsigned short*)Ain;
#pragma unroll
      for (int it = 0; it < 4; ++it) {
        int u = it * 256 + tid;
        int m = u >> 3, c = u & 7;
        int mg = bm + m; if (mg >= M) mg = M - 1;
        int4 v = *(const int4*)((const char*)(A + (size_t)mg * K + k0) + c * 16);
        int off = m * 128 + ((c * 16) ^ ((m & 7) << 4));
        *(int4*)(As + off) = v;
      }
    }
#pragma unroll
    for (int it = 0; it < 4; ++it) {
      int u = it * 256 + tid;
      int n = u >> 3, c = u & 7;
      int4 v = *(const int4*)((const char*)(Bt + (size_t)(bn + n) * ldB + k0) + c * 16);
      int off = n * 128 + ((c * 16) ^ ((n & 7) << 4));
      *(int4*)(Bs + off) = v;
    }
    __syncthreads();
#pragma unroll
    for (int kk = 0; kk < 2; ++kk) {
      int kbyte = kk * 64 + ((lane >> 4) << 4);
      short8 af[2];
#pragma unroll
      for (int mi = 0; mi < 2; ++mi) {
        int m = wv * 32 + mi * 16 + (lane & 15);
        af[mi] = *(const short8*)(As + m * 128 + (kbyte ^ ((m & 7) << 4)));
      }
#pragma unroll
      for (int ni = 0; ni < 8; ++ni) {
        int n = ni * 16 + (lane & 15);
        short8 bf = *(const short8*)(Bs + n * 128 + (kbyte ^ ((n & 7) << 4)));
#pragma unroll
        for (int mi = 0; mi < 2; ++mi)
          acc[mi][ni] = __builtin_amdgcn_mfma_f32_16x16x32_bf16(af[mi], bf, acc[mi][ni], 0, 0, 0);
      }
    }
    __syncthreads();
  }
#pragma unroll
  for (int mi = 0; mi < 2; ++mi) {
#pragma unroll
    for (int r = 0; r < 4; ++r) {
      int row = bm + wv * 32 + mi * 16 + ((lane >> 4) << 2) + r;
      if (row < M) {
#pragma unroll
        for (int ni = 0; ni < 8; ++ni) {
          int col = bn + ni * 16 + (lane & 15);
          if (col < Nstore) {
            float v = acc[mi][ni][r] + (bias ? bias[col] : 0.f);
            if (OUT_BF16)
              ((unsigned short*)Cv)[(size_t)row * ldC + col] = f32_to_bf16_bits(v);
            else
              ((float*)Cv)[(size_t)row * ldC + col] = v;
          }
        }
      }
    }
  }
}

// ================= fused layer-1: single dense CSR walk + MFMA =====================
// Block: 512 thr (8 waves), 32 dsts. Wave wv walks dsts wv*4..+4 serially in dense
// mode (all 64 lanes on one dst: lane holds feats 2l,2l+1; 8-rel sums in 24 VGPR).
// Means dumped to swizzled LDS [32][1024] bf16; root rows staged [32][128].
// Then MFMA vs W1T/rootT read straight from L2. Epilogue: +b1, relu, bf16 -> x1.
__global__ __launch_bounds__(512) void l1_mfma(
    const int* __restrict__ row_ptr, const unsigned* __restrict__ packed,
    const unsigned* __restrict__ xu, const unsigned short* __restrict__ W1T,
    const unsigned short* __restrict__ rootT, const float* __restrict__ b1,
    unsigned short* __restrict__ x1) {
  __shared__ char Ms[32 * 2048];   // 64 KB means tile
  __shared__ char Rs[32 * 256];    // 8 KB root tile
  const int tid = threadIdx.x;
  const int lane = tid & 63;
  const int wv = tid >> 6;
  const int dst0 = blockIdx.x * 32;

  // ---- dense walk (once, all 8 relations) ----
  for (int i = 0; i < 4; ++i) {
    int j = wv * 4 + i;
    int d = dst0 + j;
    float a0[8], a1[8];
    int c[8];
#pragma unroll
    for (int q = 0; q < 8; ++q) { a0[q] = 0.f; a1[q] = 0.f; c[q] = 0; }
    if (d < NNODES) {
      int beg = row_ptr[d];
      int end = (d == NNODES - 1) ? NEDGE : row_ptr[d + 1];
      for (int e = beg; e < end; ++e) {
        unsigned p = packed[e];
        unsigned t = p >> 17;
        unsigned u = xu[(size_t)(p & 0x1FFFFu) * 64 + lane];
        float lo = bf16_bits_to_f32((unsigned short)(u & 0xffffu));
        float hi = bf16_bits_to_f32((unsigned short)(u >> 16));
#pragma unroll
        for (int q = 0; q < 8; ++q) {
          bool m = (t == (unsigned)q);
          a0[q] += m ? lo : 0.f;
          a1[q] += m ? hi : 0.f;
          c[q] += m ? 1 : 0;
        }
      }
    }
#pragma unroll
    for (int q = 0; q < 8; ++q) {
      float w = 1.0f / (float)(c[q] > 0 ? c[q] : 1);
      unsigned outw = f32_to_bf16_bits(a0[q] * w) |
                      ((unsigned)f32_to_bf16_bits(a1[q] * w) << 16);
      int b0 = q * 256 + lane * 4;
      *(unsigned*)(Ms + j * 2048 + (b0 ^ ((j & 7) << 4))) = outw;
    }
  }
  // ---- stage root rows (coalesced) ----
  {
    int j = tid >> 4, c16 = tid & 15;
    int d = dst0 + j; if (d >= NNODES) d = NNODES - 1;
    int4 v = *(const int4*)((const char*)xu + (size_t)d * 256 + c16 * 16);
    *(int4*)(Rs + j * 256 + ((c16 * 16) ^ ((j & 7) << 4))) = v;
  }
  __syncthreads();

  // ---- MFMA: wave -> mfrag = wv&1, nfrags = (wv>>1)*2 + {0,1} ----
  const int mf = wv & 1;
  const int nb = wv >> 1;
  const int r16 = lane & 15;
  const int q0 = lane >> 4;
  const int arow = mf * 16 + r16;
  f32x4 acc[2] = {};
  for (int kk = 0; kk < 32; ++kk) {
    int kbyte = kk * 64 + q0 * 16;
    short8 af = *(const short8*)(Ms + arow * 2048 + (kbyte ^ ((arow & 7) << 4)));
#pragma unroll
    for (int n = 0; n < 2; ++n) {
      int ncol = (nb * 2 + n) * 16 + r16;
      short8 bf = *(const short8*)(W1T + (size_t)ncol * 1024 + kk * 32 + q0 * 8);
      acc[n] = __builtin_amdgcn_mfma_f32_16x16x32_bf16(af, bf, acc[n], 0, 0, 0);
    }
  }
#pragma unroll
  for (int kk = 0; kk < 4; ++kk) {
    int kbyte = kk * 64 + q0 * 16;
    short8 af = *(const short8*)(Rs + arow * 256 + (kbyte ^ ((arow & 7) << 4)));
#pragma unroll
    for (int n = 0; n < 2; ++n) {
      int ncol = (nb * 2 + n) * 16 + r16;
      short8 bf = *(const short8*)(rootT + (size_t)ncol * 128 + kk * 32 + q0 * 8);
      acc[n] = __builtin_amdgcn_mfma_f32_16x16x32_bf16(af, bf, acc[n], 0, 0, 0);
    }
  }
#pragma unroll
  for (int n = 0; n < 2; ++n) {
#pragma unroll
    for (int r = 0; r < 4; ++r) {
      int row = dst0 + mf * 16 + q0 * 4 + r;
      int col = (nb * 2 + n) * 16 + r16;
      if (row < NNODES) {
        float v = acc[n][r] + b1[col];
        x1[(size_t)row * 128 + col] = f32_to_bf16_bits(fmaxf(v, 0.f));
      }
    }
  }
}

// ================= weight repacks ==================================================
__global__ void build_Bt(const float* __restrict__ W, unsigned short* __restrict__ Wt,
                         int K, int N) {
  int idx = blockIdx.x * blockDim.x + threadIdx.x;
  if (idx >= N * K) return;
  int n = idx / K, k = idx - n * K;
  Wt[idx] = f32_to_bf16_bits(W[(size_t)k * N + n]);
}

// W1 [8,128,128] -> W1T [128 f][1024]: W1T[f][t*128+k] = W1[t][k][f]
__global__ void build_W1T(const float* __restrict__ W1, unsigned short* __restrict__ Wt) {
  int idx = blockIdx.x * blockDim.x + threadIdx.x;
  if (idx >= 128 * 1024) return;
  int f = idx >> 10, c = idx & 1023;
  int t = c >> 7, k = c & 127;
  Wt[idx] = f32_to_bf16_bits(W1[((size_t)t * 128 + k) * 128 + f]);
}

// B2pad [128][128] bf16: n<16: W2[n>>1][k][n&1]; 16<=n<18: root2[k][n-16]; else 0
__global__ void build_B2pad(const float* __restrict__ W2, const float* __restrict__ root2,
                            unsigned short* __restrict__ Bt) {
  int idx = blockIdx.x * blockDim.x + threadIdx.x;
  if (idx >= 128 * 128) return;
  int n = idx >> 7, k = idx & 127;
  float v = 0.f;
  if (n < 16) v = W2[((size_t)(n >> 1) * 128 + k) * 2 + (n & 1)];
  else if (n < 18) v = root2[(size_t)k * 2 + (n - 16)];
  Bt[idx] = f32_to_bf16_bits(v);
}

// ================= CSR build =======================================================
__global__ void count_dst(const int* __restrict__ ei, int* __restrict__ cnt_dst) {
  int e = blockIdx.x * blockDim.x + threadIdx.x;
  int stride = gridDim.x * blockDim.x;
  for (; e < NEDGE; e += stride) {
    unsigned d = (unsigned)ei[NEDGE + e]; if (d >= NNODES) d = 0;
    atomicAdd(cnt_dst + d, 1);
  }
}

__global__ void scan_block(const int* __restrict__ in, int* __restrict__ out,
                           int* __restrict__ bsum, int n) {
  __shared__ int s[SCAN_B];
  int i = blockIdx.x * SCAN_B + threadIdx.x;
  int x = (i < n) ? in[i] : 0;
  s[threadIdx.x] = x;
  __syncthreads();
  for (int d = 1; d < SCAN_B; d <<= 1) {
    int v = (threadIdx.x >= d) ? s[threadIdx.x - d] : 0;
    __syncthreads();
    s[threadIdx.x] += v;
    __syncthreads();
  }
  if (i < n) out[i] = s[threadIdx.x] - x;
  if (threadIdx.x == SCAN_B - 1) bsum[blockIdx.x] = s[threadIdx.x];
}

__global__ void scan_top(int* __restrict__ bsum, int* __restrict__ bofs, int nb) {
  __shared__ int s[512];
  int x = (threadIdx.x < nb) ? bsum[threadIdx.x] : 0;
  s[threadIdx.x] = x;
  __syncthreads();
  for (int d = 1; d < 512; d <<= 1) {
    int v = (threadIdx.x >= d) ? s[threadIdx.x - d] : 0;
    __syncthreads();
    s[threadIdx.x] += v;
    __syncthreads();
  }
  if (threadIdx.x < nb) bofs[threadIdx.x] = s[threadIdx.x] - x;
}

__global__ void scan_apply(int* __restrict__ row_ptr, const int* __restrict__ bofs,
                           int* __restrict__ slot, int n) {
  int i = blockIdx.x * blockDim.x + threadIdx.x;
  if (i >= n) return;
  int v = row_ptr[i] + bofs[i / SCAN_B];
  row_ptr[i] = v;
  slot[i] = v;
}

__global__ void scatter_edges(const int* __restrict__ ei, const int* __restrict__ et,
                              int* __restrict__ slot, unsigned* __restrict__ packed) {
  int e = blockIdx.x * blockDim.x + threadIdx.x;
  int stride = gridDim.x * blockDim.x;
  for (; e < NEDGE; e += stride) {
    unsigned s = (unsigned)ei[e];         if (s >= NNODES) s = 0;
    unsigned d = (unsigned)ei[NEDGE + e]; if (d >= NNODES) d = 0;
    unsigned t = (unsigned)et[e];         if (t >= NREL)  t = 0;
    int pos = atomicAdd(slot + d, 1);
    packed[pos] = (t << 17) | s;
  }
}

// ============ layer-2 aggregation + log_softmax (4 lanes per dst) ==================
__global__ void fused_out(const int* __restrict__ row_ptr, const unsigned* __restrict__ packed,
                          const float* __restrict__ h2, const float* __restrict__ b2,
                          float* __restrict__ out) {
  int gt = blockIdx.x * blockDim.x + threadIdx.x;
  int d = gt >> 2;
  int l4 = gt & 3;
  if (d >= NNODES) return;
  int beg = row_ptr[d];
  int end = (d == NNODES - 1) ? NEDGE : row_ptr[d + 1];
  int cnts[8];
#pragma unroll
  for (int q = 0; q < 8; ++q) cnts[q] = 0;
  for (int e = beg; e < end; ++e) {
    unsigned t = packed[e] >> 17;
#pragma unroll
    for (int q = 0; q < 8; ++q) cnts[q] += (t == (unsigned)q);
  }
  float z0 = 0.f, z1 = 0.f;
  for (int e = beg + l4; e < end; e += 4) {
    unsigned p = packed[e];
    unsigned s = p & 0x1FFFFu;
    unsigned t = p >> 17;
    int ct = 1;
#pragma unroll
    for (int q = 0; q < 8; ++q) ct = (t == (unsigned)q) ? cnts[q] : ct;
    float w = 1.0f / (float)(ct > 0 ? ct : 1);
    z0 = fmaf(h2[(size_t)s * 18 + t * 2], w, z0);
    z1 = fmaf(h2[(size_t)s * 18 + t * 2 + 1], w, z1);
  }
  z0 += __shfl_xor(z0, 1, 4); z0 += __shfl_xor(z0, 2, 4);
  z1 += __shfl_xor(z1, 1, 4); z1 += __shfl_xor(z1, 2, 4);
  if (l4 == 0) {
    z0 += h2[(size_t)d * 18 + 16] + b2[0];
    z1 += h2[(size_t)d * 18 + 17] + b2[1];
    float m = fmaxf(z0, z1);
    float l = m + logf(expf(z0 - m) + expf(z1 - m));
    out[(size_t)d * 2 + 0] = z0 - l;
    out[(size_t)d * 2 + 1] = z1 - l;
  }
}

__global__ void fill_sentinel(float* __restrict__ out, int n, float v) {
  int i = blockIdx.x * blockDim.x + threadIdx.x;
  if (i < n) out[i] = v;
}

// ===================================================================================
extern "C" void kernel_launch(void* const* d_in, const int* in_sizes, int n_in,
                              void* d_out, int out_size, void* d_ws, size_t ws_size,
                              hipStream_t stream) {
  const float* x_user = (const float*)d_in[0];
  const float* x_food = (const float*)d_in[1];
  const float* x_ing  = (const float*)d_in[2];
  const float* x_cat  = (const float*)d_in[3];
  const float* x_hab  = (const float*)d_in[4];
  const float* Wu = (const float*)d_in[5];  const float* bu  = (const float*)d_in[6];
  const float* Wf = (const float*)d_in[7];  const float* bfo = (const float*)d_in[8];
  const float* Wi = (const float*)d_in[9];  const float* bi  = (const float*)d_in[10];
  const float* Wc = (const float*)d_in[11]; const float* bc  = (const float*)d_in[12];
  const float* Wh = (const float*)d_in[13]; const float* bh  = (const float*)d_in[14];
  const float* W1 = (const float*)d_in[15]; const float* root1 = (const float*)d_in[16];
  const float* b1 = (const float*)d_in[17];
  const float* W2 = (const float*)d_in[18]; const float* root2 = (const float*)d_in[19];
  const float* b2 = (const float*)d_in[20];
  const int* ei = (const int*)d_in[21];
  const int* et = (const int*)d_in[22];
  (void)in_sizes; (void)n_in;

  dim3 blk(256);
  const int NB1 = (NNODES + SCAN_B - 1) / SCAN_B;   // 450

  // ---- workspace (~75 MB) ----
  char* ws = (char*)d_ws;
  size_t off = 0;
  unsigned short* x_all = (unsigned short*)(ws + off); off += alignup((size_t)NNODES * 128 * 2);
  unsigned short* x1    = (unsigned short*)(ws + off); off += alignup((size_t)NNODES * 128 * 2);
  int* cnt_dst = (int*)(ws + off);       off += alignup((size_t)NNODES * 4);
  int* row_ptr = (int*)(ws + off);       off += alignup((size_t)NNODES * 4);
  int* slot = (int*)(ws + off);          off += alignup((size_t)NNODES * 4);
  unsigned* packed = (unsigned*)(ws + off); off += alignup((size_t)NEDGE * 4);
  int* bsum = (int*)(ws + off);          off += alignup((size_t)512 * 4);
  int* bofs = (int*)(ws + off);          off += alignup((size_t)512 * 4);
  unsigned short* WuT = (unsigned short*)(ws + off); off += alignup((size_t)128 * 256 * 2);
  unsigned short* WfT = (unsigned short*)(ws + off); off += alignup((size_t)128 * 512 * 2);
  unsigned short* WiT = (unsigned short*)(ws + off); off += alignup((size_t)128 * 128 * 2);
  unsigned short* WcT = (unsigned short*)(ws + off); off += alignup((size_t)128 * 64 * 2);
  unsigned short* WhT = (unsigned short*)(ws + off); off += alignup((size_t)128 * 64 * 2);
  unsigned short* rootT = (unsigned short*)(ws + off); off += alignup((size_t)128 * 128 * 2);
  unsigned short* W1T = (unsigned short*)(ws + off); off += alignup((size_t)128 * 1024 * 2);
  unsigned short* B2pad = (unsigned short*)(ws + off); off += alignup((size_t)128 * 128 * 2);
  float* h2 = (float*)(ws + off);        off += alignup((size_t)NNODES * 18 * 4);
  size_t needed = off;

  if (ws_size < needed) {
    fill_sentinel<<<(out_size + 255) / 256, blk, 0, stream>>>((float*)d_out, out_size, -777.0f);
    return;
  }

  hipMemsetAsync(cnt_dst, 0, (size_t)NNODES * 4, stream);

  // ---- weight repacks ----
  build_Bt<<<(128 * 256 + 255) / 256, blk, 0, stream>>>(Wu, WuT, 256, 128);
  build_Bt<<<(128 * 512 + 255) / 256, blk, 0, stream>>>(Wf, WfT, 512, 128);
  build_Bt<<<(128 * 128 + 255) / 256, blk, 0, stream>>>(Wi, WiT, 128, 128);
  build_Bt<<<(128 * 64 + 255) / 256, blk, 0, stream>>>(Wc, WcT, 64, 128);
  build_Bt<<<(128 * 64 + 255) / 256, blk, 0, stream>>>(Wh, WhT, 64, 128);
  build_Bt<<<(128 * 128 + 255) / 256, blk, 0, stream>>>(root1, rootT, 128, 128);
  build_W1T<<<(128 * 1024 + 255) / 256, blk, 0, stream>>>(W1, W1T);
  build_B2pad<<<(128 * 128 + 255) / 256, blk, 0, stream>>>(W2, root2, B2pad);

  // ---- projections -> x_all (bf16) ----
  { dim3 g(1, (NU + 127) / 128);
    mfma_gemm<true, true><<<g, blk, 0, stream>>>(x_user, WuT, 256, bu, (void*)x_all, 128, 128, NU, 128, 256); }
  { dim3 g(1, (NFOOD + 127) / 128);
    mfma_gemm<true, true><<<g, blk, 0, stream>>>(x_food, WfT, 512, bfo, (void*)(x_all + (size_t)NU * 128), 128, 128, NFOOD, 128, 512); }
  { dim3 g(1, (NING + 127) / 128);
    mfma_gemm<true, true><<<g, blk, 0, stream>>>(x_ing, WiT, 128, bi, (void*)(x_all + (size_t)(NU + NFOOD) * 128), 128, 128, NING, 128, 128); }
  { dim3 g(1, (NCAT + 127) / 128);
    mfma_gemm<true, true><<<g, blk, 0, stream>>>(x_cat, WcT, 64, bc, (void*)(x_all + (size_t)(NU + NFOOD + NING) * 128), 128, 128, NCAT, 128, 64); }
  { dim3 g(1, (NHAB + 127) / 128);
    mfma_gemm<true, true><<<g, blk, 0, stream>>>(x_hab, WhT, 64, bh, (void*)(x_all + (size_t)(NU + NFOOD + NING + NCAT) * 128), 128, 128, NHAB, 128, 64); }

  // ---- CSR build ----
  count_dst<<<2048, blk, 0, stream>>>(ei, cnt_dst);
  scan_block<<<NB1, SCAN_B, 0, stream>>>(cnt_dst, row_ptr, bsum, NNODES);
  scan_top<<<1, 512, 0, stream>>>(bsum, bofs, NB1);
  scan_apply<<<NB1, SCAN_B, 0, stream>>>(row_ptr, bofs, slot, NNODES);
  scatter_edges<<<2048, blk, 0, stream>>>(ei, et, slot, packed);

  // ---- fused layer-1 ----
  l1_mfma<<<(NNODES + 31) / 32, dim3(512), 0, stream>>>(
      row_ptr, packed, (const unsigned*)x_all, W1T, rootT, b1, x1);

  // ---- layer 2: h2 = x1 @ B2pad (store 18 cols) ----
  { dim3 g(1, (NNODES + 127) / 128);
    mfma_gemm<false, false><<<g, blk, 0, stream>>>(x1, B2pad, 128, nullptr, (void*)h2, 18, 18, NNODES, 128, 128); }

  fused_out<<<(NNODES * 4 + 255) / 256, blk, 0, stream>>>(row_ptr, packed, h2, b2, (float*)d_out);
}

// Round 8
// 746.180 us; speedup vs baseline: 1.2076x; 1.2076x over previous
//
#include <hip/hip_runtime.h>
#include <hip/hip_bf16.h>
#include <math.h>

#define NU 50000
#define NFOOD 30000
#define NING 20000
#define NCAT 5000
#define NHAB 10000
#define NNODES 115000
#define NCHUNK 14375   // NNODES/8
#define NREL 8
#define NEDGE 1500000
#define SCAN_B 256

typedef __attribute__((ext_vector_type(8))) short short8;
typedef __attribute__((ext_vector_type(4))) float f32x4;

static inline size_t alignup(size_t x) { return (x + 255) & ~(size_t)255; }

__device__ inline float bf16_bits_to_f32(unsigned short u) {
  return __uint_as_float(((unsigned)u) << 16);
}
__device__ inline unsigned short f32_to_bf16_bits(float f) {
  unsigned u = __float_as_uint(f);
  unsigned r = u + 0x7fffu + ((u >> 16) & 1u);
  return (unsigned short)(r >> 16);
}

// ================= MFMA bf16 GEMM ==================================================
// C[M,N] = op(A)[M,K] @ B_T[N,K] (+bias) (+C if ACC). A row-major, lda==K.
// Bt [N][ldB] bf16. Tile 128x128, BK=64, 256 thr. LDS XOR swizzle byte^=(row&7)<<4.
// RELU_A: relu in f32 A-staging. RELU_OUT: relu before store.
template <bool A_F32, bool OUT_BF16, bool RELU_A, bool RELU_OUT, bool ACC>
__global__ __launch_bounds__(256) void mfma_gemm(
    const void* __restrict__ Ain, const unsigned short* __restrict__ Bt, int ldB,
    const float* __restrict__ bias, void* __restrict__ Cv, int ldC, int Nstore,
    int M, int N, int K) {
  __shared__ char As[128 * 128];
  __shared__ char Bs[128 * 128];
  const int tid = threadIdx.x;
  const int lane = tid & 63;
  const int wv = tid >> 6;
  const int bm = blockIdx.y * 128;
  const int bn = blockIdx.x * 128;
  f32x4 acc[2][8] = {};

  for (int k0 = 0; k0 < K; k0 += 64) {
    if (A_F32) {
      const float* A = (const float*)Ain;
#pragma unroll
      for (int it = 0; it < 4; ++it) {
        int u = it * 256 + tid;
        int m = u >> 3, c = u & 7;
        int mg = bm + m; if (mg >= M) mg = M - 1;
        const float4* src = (const float4*)(A + (size_t)mg * K + k0 + c * 8);
        float4 lo4 = src[0], hi4 = src[1];
        if (RELU_A) {
          lo4.x = fmaxf(lo4.x, 0.f); lo4.y = fmaxf(lo4.y, 0.f);
          lo4.z = fmaxf(lo4.z, 0.f); lo4.w = fmaxf(lo4.w, 0.f);
          hi4.x = fmaxf(hi4.x, 0.f); hi4.y = fmaxf(hi4.y, 0.f);
          hi4.z = fmaxf(hi4.z, 0.f); hi4.w = fmaxf(hi4.w, 0.f);
        }
        unsigned q0 = f32_to_bf16_bits(lo4.x) | ((unsigned)f32_to_bf16_bits(lo4.y) << 16);
        unsigned q1 = f32_to_bf16_bits(lo4.z) | ((unsigned)f32_to_bf16_bits(lo4.w) << 16);
        unsigned q2 = f32_to_bf16_bits(hi4.x) | ((unsigned)f32_to_bf16_bits(hi4.y) << 16);
        unsigned q3 = f32_to_bf16_bits(hi4.z) | ((unsigned)f32_to_bf16_bits(hi4.w) << 16);
        int off = m * 128 + ((c * 16) ^ ((m & 7) << 4));
        *(int4*)(As + off) = make_int4(q0, q1, q2, q3);
      }
    } else {
      const unsigned short* A = (const unsigned short*)Ain;
#pragma unroll
      for (int it = 0; it < 4; ++it) {
        int u = it * 256 + tid;
        int m = u >> 3, c = u & 7;
        int mg = bm + m; if (mg >= M) mg = M - 1;
        int4 v = *(const int4*)((const char*)(A + (size_t)mg * K + k0) + c * 16);
        int off = m * 128 + ((c * 16) ^ ((m & 7) << 4));
        *(int4*)(As + off) = v;
      }
    }
#pragma unroll
    for (int it = 0; it < 4; ++it) {
      int u = it * 256 + tid;
      int n = u >> 3, c = u & 7;
      int4 v = *(const int4*)((const char*)(Bt + (size_t)(bn + n) * ldB + k0) + c * 16);
      int off = n * 128 + ((c * 16) ^ ((n & 7) << 4));
      *(int4*)(Bs + off) = v;
    }
    __syncthreads();
#pragma unroll
    for (int kk = 0; kk < 2; ++kk) {
      int kbyte = kk * 64 + ((lane >> 4) << 4);
      short8 af[2];
#pragma unroll
      for (int mi = 0; mi < 2; ++mi) {
        int m = wv * 32 + mi * 16 + (lane & 15);
        af[mi] = *(const short8*)(As + m * 128 + (kbyte ^ ((m & 7) << 4)));
      }
#pragma unroll
      for (int ni = 0; ni < 8; ++ni) {
        int n = ni * 16 + (lane & 15);
        short8 bf = *(const short8*)(Bs + n * 128 + (kbyte ^ ((n & 7) << 4)));
#pragma unroll
        for (int mi = 0; mi < 2; ++mi)
          acc[mi][ni] = __builtin_amdgcn_mfma_f32_16x16x32_bf16(af[mi], bf, acc[mi][ni], 0, 0, 0);
      }
    }
    __syncthreads();
  }
#pragma unroll
  for (int mi = 0; mi < 2; ++mi) {
#pragma unroll
    for (int r = 0; r < 4; ++r) {
      int row = bm + wv * 32 + mi * 16 + ((lane >> 4) << 2) + r;
      if (row < M) {
#pragma unroll
        for (int ni = 0; ni < 8; ++ni) {
          int col = bn + ni * 16 + (lane & 15);
          if (col < Nstore) {
            float v = acc[mi][ni][r] + (bias ? bias[col] : 0.f);
            if (ACC) v += ((const float*)Cv)[(size_t)row * ldC + col];
            if (RELU_OUT) v = fmaxf(v, 0.f);
            if (OUT_BF16)
              ((unsigned short*)Cv)[(size_t)row * ldC + col] = f32_to_bf16_bits(v);
            else
              ((float*)Cv)[(size_t)row * ldC + col] = v;
          }
        }
      }
    }
  }
}

// ================= weight repacks ==================================================
__global__ void build_Bt(const float* __restrict__ W, unsigned short* __restrict__ Wt,
                         int K, int N) {
  int idx = blockIdx.x * blockDim.x + threadIdx.x;
  if (idx >= N * K) return;
  int n = idx / K, k = idx - n * K;
  Wt[idx] = f32_to_bf16_bits(W[(size_t)k * N + n]);
}

// W1rT [128 f][1152]: cols t*128+k = W1[t][k][f] (t<8); cols 1024+k = root1[k][f]
__global__ void build_W1rT(const float* __restrict__ W1, const float* __restrict__ root1,
                           unsigned short* __restrict__ Wt) {
  int idx = blockIdx.x * blockDim.x + threadIdx.x;
  if (idx >= 128 * 1152) return;
  int f = idx / 1152, c = idx - f * 1152;
  float v;
  if (c < 1024) { int t = c >> 7, k = c & 127; v = W1[((size_t)t * 128 + k) * 128 + f]; }
  else { int k = c - 1024; v = root1[(size_t)k * 128 + f]; }
  Wt[idx] = f32_to_bf16_bits(v);
}

// B2pad [128][128] bf16: n<16: W2[n>>1][k][n&1]; 16<=n<18: root2[k][n-16]; else 0
__global__ void build_B2pad(const float* __restrict__ W2, const float* __restrict__ root2,
                            unsigned short* __restrict__ Bt) {
  int idx = blockIdx.x * blockDim.x + threadIdx.x;
  if (idx >= 128 * 128) return;
  int n = idx >> 7, k = idx & 127;
  float v = 0.f;
  if (n < 16) v = W2[((size_t)(n >> 1) * 128 + k) * 2 + (n & 1)];
  else if (n < 18) v = root2[(size_t)k * 2 + (n - 16)];
  Bt[idx] = f32_to_bf16_bits(v);
}

// ================= CSR build (XCD-partitioned by dst chunk) ========================
__global__ void count_dst_xcd(const int* __restrict__ ei, int* __restrict__ cnt_dst) {
  int cls = blockIdx.x & 7;
  unsigned lo = cls * NCHUNK, hi = lo + NCHUNK;
  int e = (blockIdx.x >> 3) * blockDim.x + threadIdx.x;
  int stride = (gridDim.x >> 3) * blockDim.x;
  for (; e < NEDGE; e += stride) {
    unsigned d = (unsigned)ei[NEDGE + e]; if (d >= NNODES) d = 0;
    if (d < lo || d >= hi) continue;
    atomicAdd(cnt_dst + d, 1);
  }
}

__global__ void scan_block(const int* __restrict__ in, int* __restrict__ out,
                           int* __restrict__ bsum, int n) {
  __shared__ int s[SCAN_B];
  int i = blockIdx.x * SCAN_B + threadIdx.x;
  int x = (i < n) ? in[i] : 0;
  s[threadIdx.x] = x;
  __syncthreads();
  for (int d = 1; d < SCAN_B; d <<= 1) {
    int v = (threadIdx.x >= d) ? s[threadIdx.x - d] : 0;
    __syncthreads();
    s[threadIdx.x] += v;
    __syncthreads();
  }
  if (i < n) out[i] = s[threadIdx.x] - x;
  if (threadIdx.x == SCAN_B - 1) bsum[blockIdx.x] = s[threadIdx.x];
}

__global__ void scan_top(int* __restrict__ bsum, int* __restrict__ bofs, int nb) {
  __shared__ int s[512];
  int x = (threadIdx.x < nb) ? bsum[threadIdx.x] : 0;
  s[threadIdx.x] = x;
  __syncthreads();
  for (int d = 1; d < 512; d <<= 1) {
    int v = (threadIdx.x >= d) ? s[threadIdx.x - d] : 0;
    __syncthreads();
    s[threadIdx.x] += v;
    __syncthreads();
  }
  if (threadIdx.x < nb) bofs[threadIdx.x] = s[threadIdx.x] - x;
}

__global__ void scan_apply(int* __restrict__ row_ptr, const int* __restrict__ bofs,
                           int* __restrict__ slot, int n) {
  int i = blockIdx.x * blockDim.x + threadIdx.x;
  if (i >= n) return;
  int v = row_ptr[i] + bofs[i / SCAN_B];
  row_ptr[i] = v;
  slot[i] = v;
}

__global__ void scatter_edges_xcd(const int* __restrict__ ei, const int* __restrict__ et,
                                  int* __restrict__ slot, unsigned* __restrict__ packed) {
  int cls = blockIdx.x & 7;
  unsigned lo = cls * NCHUNK, hi = lo + NCHUNK;
  int e = (blockIdx.x >> 3) * blockDim.x + threadIdx.x;
  int stride = (gridDim.x >> 3) * blockDim.x;
  for (; e < NEDGE; e += stride) {
    unsigned d = (unsigned)ei[NEDGE + e]; if (d >= NNODES) d = 0;
    if (d < lo || d >= hi) continue;
    unsigned s = (unsigned)ei[e];  if (s >= NNODES) s = 0;
    unsigned t = (unsigned)et[e];  if (t >= NREL)  t = 0;
    int pos = atomicAdd(slot + d, 1);
    packed[pos] = (t << 17) | s;
  }
}

// ============ layer-1 gather-means, all 8 relations, one pass (wave per dst) =======
// M9[d] = [8 x 128 means | x_all[d]] bf16 (1152 cols); cnt8[d][t] u16 counts.
__global__ __launch_bounds__(256) void gather_means8(
    const int* __restrict__ row_ptr, const unsigned* __restrict__ packed,
    const unsigned* __restrict__ xu, unsigned* __restrict__ M9,
    unsigned short* __restrict__ cnt8) {
  int lane = threadIdx.x & 63;
  int wid = (blockIdx.x * blockDim.x + threadIdx.x) >> 6;
  int nw = (gridDim.x * blockDim.x) >> 6;
  for (int d = wid; d < NNODES; d += nw) {
    int beg = row_ptr[d];
    int end = (d == NNODES - 1) ? NEDGE : row_ptr[d + 1];
    float a0[8], a1[8];
    int c[8];
#pragma unroll
    for (int q = 0; q < 8; ++q) { a0[q] = 0.f; a1[q] = 0.f; c[q] = 0; }
    for (int e = beg; e < end; ++e) {
      unsigned p = packed[e];
      unsigned t = p >> 17;
      unsigned u = xu[(size_t)(p & 0x1FFFFu) * 64 + lane];
      float lo = bf16_bits_to_f32((unsigned short)(u & 0xffffu));
      float hi = bf16_bits_to_f32((unsigned short)(u >> 16));
#pragma unroll
      for (int q = 0; q < 8; ++q) {
        bool m = (t == (unsigned)q);
        a0[q] += m ? lo : 0.f;
        a1[q] += m ? hi : 0.f;
        c[q] += m ? 1 : 0;
      }
    }
    unsigned* rowp = M9 + (size_t)d * 576;   // 1152 bf16 = 576 u32
#pragma unroll
    for (int q = 0; q < 8; ++q) {
      float w = 1.0f / (float)(c[q] > 0 ? c[q] : 1);
      rowp[q * 64 + lane] = f32_to_bf16_bits(a0[q] * w) |
                            ((unsigned)f32_to_bf16_bits(a1[q] * w) << 16);
    }
    rowp[512 + lane] = xu[(size_t)d * 64 + lane];   // root block = x_all row
    if (lane == 0) {
      uint4 cw;
      cw.x = (unsigned)c[0] | ((unsigned)c[1] << 16);
      cw.y = (unsigned)c[2] | ((unsigned)c[3] << 16);
      cw.z = (unsigned)c[4] | ((unsigned)c[5] << 16);
      cw.w = (unsigned)c[6] | ((unsigned)c[7] << 16);
      *(uint4*)(cnt8 + (size_t)d * 8) = cw;
    }
  }
}

// ============ layer-1 gather-means, relation block of 4 (fallback path) ============
__global__ __launch_bounds__(256) void gather_means4(
    const int* __restrict__ row_ptr, const unsigned* __restrict__ packed,
    const unsigned* __restrict__ xu, unsigned* __restrict__ Mb,
    unsigned short* __restrict__ cnt8, int rb0) {
  int lane = threadIdx.x & 63;
  int wid = (blockIdx.x * blockDim.x + threadIdx.x) >> 6;
  int nw = (gridDim.x * blockDim.x) >> 6;
  for (int d = wid; d < NNODES; d += nw) {
    int beg = row_ptr[d];
    int end = (d == NNODES - 1) ? NEDGE : row_ptr[d + 1];
    float a0[4], a1[4];
    int c[4];
#pragma unroll
    for (int q = 0; q < 4; ++q) { a0[q] = 0.f; a1[q] = 0.f; c[q] = 0; }
    for (int e = beg; e < end; ++e) {
      unsigned p = packed[e];
      int tt = (int)(p >> 17) - rb0;
      if ((unsigned)tt >= 4u) continue;
      unsigned u = xu[(size_t)(p & 0x1FFFFu) * 64 + lane];
      float lo = bf16_bits_to_f32((unsigned short)(u & 0xffffu));
      float hi = bf16_bits_to_f32((unsigned short)(u >> 16));
#pragma unroll
      for (int q = 0; q < 4; ++q) {
        bool m = (tt == q);
        a0[q] += m ? lo : 0.f;
        a1[q] += m ? hi : 0.f;
        c[q] += m ? 1 : 0;
      }
    }
#pragma unroll
    for (int q = 0; q < 4; ++q) {
      float w = 1.0f / (float)(c[q] > 0 ? c[q] : 1);
      Mb[(size_t)d * 256 + q * 64 + lane] = f32_to_bf16_bits(a0[q] * w) |
                                            ((unsigned)f32_to_bf16_bits(a1[q] * w) << 16);
    }
    if (lane == 0) {
      uint2 cw;
      cw.x = (unsigned)c[0] | ((unsigned)c[1] << 16);
      cw.y = (unsigned)c[2] | ((unsigned)c[3] << 16);
      *(uint2*)(cnt8 + (size_t)d * 8 + rb0) = cw;
    }
  }
}

// ============ layer-2 aggregation + log_softmax (4 lanes per dst, cnt8-based) ======
__global__ void fused_out(const int* __restrict__ row_ptr, const unsigned* __restrict__ packed,
                          const unsigned short* __restrict__ cnt8,
                          const float* __restrict__ h2, const float* __restrict__ b2,
                          float* __restrict__ out) {
  int gt = blockIdx.x * blockDim.x + threadIdx.x;
  int d = gt >> 2;
  int l4 = gt & 3;
  if (d >= NNODES) return;
  int beg = row_ptr[d];
  int end = (d == NNODES - 1) ? NEDGE : row_ptr[d + 1];
  uint4 cw = *(const uint4*)(cnt8 + (size_t)d * 8);
  float wr[8];
  wr[0] = 1.0f / (float)((cw.x & 0xffffu) ? (cw.x & 0xffffu) : 1u);
  wr[1] = 1.0f / (float)((cw.x >> 16) ? (cw.x >> 16) : 1u);
  wr[2] = 1.0f / (float)((cw.y & 0xffffu) ? (cw.y & 0xffffu) : 1u);
  wr[3] = 1.0f / (float)((cw.y >> 16) ? (cw.y >> 16) : 1u);
  wr[4] = 1.0f / (float)((cw.z & 0xffffu) ? (cw.z & 0xffffu) : 1u);
  wr[5] = 1.0f / (float)((cw.z >> 16) ? (cw.z >> 16) : 1u);
  wr[6] = 1.0f / (float)((cw.w & 0xffffu) ? (cw.w & 0xffffu) : 1u);
  wr[7] = 1.0f / (float)((cw.w >> 16) ? (cw.w >> 16) : 1u);
  float z0 = 0.f, z1 = 0.f;
  for (int e = beg + l4; e < end; e += 4) {
    unsigned p = packed[e];
    unsigned s = p & 0x1FFFFu;
    unsigned t = p >> 17;
    float w = 1.f;
#pragma unroll
    for (int q = 0; q < 8; ++q) w = (t == (unsigned)q) ? wr[q] : w;
    z0 = fmaf(h2[(size_t)s * 18 + t * 2], w, z0);
    z1 = fmaf(h2[(size_t)s * 18 + t * 2 + 1], w, z1);
  }
  z0 += __shfl_xor(z0, 1, 4); z0 += __shfl_xor(z0, 2, 4);
  z1 += __shfl_xor(z1, 1, 4); z1 += __shfl_xor(z1, 2, 4);
  if (l4 == 0) {
    z0 += h2[(size_t)d * 18 + 16] + b2[0];
    z1 += h2[(size_t)d * 18 + 17] + b2[1];
    float m = fmaxf(z0, z1);
    float l = m + logf(expf(z0 - m) + expf(z1 - m));
    out[(size_t)d * 2 + 0] = z0 - l;
    out[(size_t)d * 2 + 1] = z1 - l;
  }
}

__global__ void fill_sentinel(float* __restrict__ out, int n, float v) {
  int i = blockIdx.x * blockDim.x + threadIdx.x;
  if (i < n) out[i] = v;
}

// ===================================================================================
extern "C" void kernel_launch(void* const* d_in, const int* in_sizes, int n_in,
                              void* d_out, int out_size, void* d_ws, size_t ws_size,
                              hipStream_t stream) {
  const float* x_user = (const float*)d_in[0];
  const float* x_food = (const float*)d_in[1];
  const float* x_ing  = (const float*)d_in[2];
  const float* x_cat  = (const float*)d_in[3];
  const float* x_hab  = (const float*)d_in[4];
  const float* Wu = (const float*)d_in[5];  const float* bu  = (const float*)d_in[6];
  const float* Wf = (const float*)d_in[7];  const float* bfo = (const float*)d_in[8];
  const float* Wi = (const float*)d_in[9];  const float* bi  = (const float*)d_in[10];
  const float* Wc = (const float*)d_in[11]; const float* bc  = (const float*)d_in[12];
  const float* Wh = (const float*)d_in[13]; const float* bh  = (const float*)d_in[14];
  const float* W1 = (const float*)d_in[15]; const float* root1 = (const float*)d_in[16];
  const float* b1 = (const float*)d_in[17];
  const float* W2 = (const float*)d_in[18]; const float* root2 = (const float*)d_in[19];
  const float* b2 = (const float*)d_in[20];
  const int* ei = (const int*)d_in[21];
  const int* et = (const int*)d_in[22];
  (void)in_sizes; (void)n_in;

  dim3 blk(256);
  const int NB1 = (NNODES + SCAN_B - 1) / SCAN_B;   // 450

  // ---- common base layout ----
  char* ws = (char*)d_ws;
  size_t off = 0;
  unsigned short* x_all = (unsigned short*)(ws + off); off += alignup((size_t)NNODES * 128 * 2);
  int* cnt_dst = (int*)(ws + off);       off += alignup((size_t)NNODES * 4);
  int* row_ptr = (int*)(ws + off);       off += alignup((size_t)NNODES * 4);
  int* slot = (int*)(ws + off);          off += alignup((size_t)NNODES * 4);
  unsigned* packed = (unsigned*)(ws + off); off += alignup((size_t)NEDGE * 4);
  int* bsum = (int*)(ws + off);          off += alignup((size_t)512 * 4);
  int* bofs = (int*)(ws + off);          off += alignup((size_t)512 * 4);
  unsigned short* WuT = (unsigned short*)(ws + off); off += alignup((size_t)128 * 256 * 2);
  unsigned short* WfT = (unsigned short*)(ws + off); off += alignup((size_t)128 * 512 * 2);
  unsigned short* WiT = (unsigned short*)(ws + off); off += alignup((size_t)128 * 128 * 2);
  unsigned short* WcT = (unsigned short*)(ws + off); off += alignup((size_t)128 * 64 * 2);
  unsigned short* WhT = (unsigned short*)(ws + off); off += alignup((size_t)128 * 64 * 2);
  unsigned short* rootT = (unsigned short*)(ws + off); off += alignup((size_t)128 * 128 * 2);
  unsigned short* W1rT = (unsigned short*)(ws + off); off += alignup((size_t)128 * 1152 * 2);
  unsigned short* B2pad = (unsigned short*)(ws + off); off += alignup((size_t)128 * 128 * 2);
  unsigned short* cnt8 = (unsigned short*)(ws + off); off += alignup((size_t)NNODES * 8 * 2);
  float* h2 = (float*)(ws + off);        off += alignup((size_t)NNODES * 18 * 4);
  size_t base = off;

  // path A: M9 tail [115000][1152] bf16; x1 aliases x_all (dead after gather)
  size_t need_A = base + alignup((size_t)NNODES * 1152 * 2);
  // path B: agg1 f32 + M_blk [115000][512] bf16
  size_t need_B = base + alignup((size_t)NNODES * 128 * 4) + alignup((size_t)NNODES * 512 * 2);

  const bool pathA = (ws_size >= need_A);
  if (!pathA && ws_size < need_B) {
    fill_sentinel<<<(out_size + 255) / 256, blk, 0, stream>>>((float*)d_out, out_size, -777.0f);
    return;
  }

  hipMemsetAsync(cnt_dst, 0, (size_t)NNODES * 4, stream);

  // ---- weight repacks ----
  build_Bt<<<(128 * 256 + 255) / 256, blk, 0, stream>>>(Wu, WuT, 256, 128);
  build_Bt<<<(128 * 512 + 255) / 256, blk, 0, stream>>>(Wf, WfT, 512, 128);
  build_Bt<<<(128 * 128 + 255) / 256, blk, 0, stream>>>(Wi, WiT, 128, 128);
  build_Bt<<<(128 * 64 + 255) / 256, blk, 0, stream>>>(Wc, WcT, 64, 128);
  build_Bt<<<(128 * 64 + 255) / 256, blk, 0, stream>>>(Wh, WhT, 64, 128);
  build_Bt<<<(128 * 128 + 255) / 256, blk, 0, stream>>>(root1, rootT, 128, 128);
  build_W1rT<<<(128 * 1152 + 255) / 256, blk, 0, stream>>>(W1, root1, W1rT);
  build_B2pad<<<(128 * 128 + 255) / 256, blk, 0, stream>>>(W2, root2, B2pad);

  // ---- projections -> x_all (bf16) ----
  { dim3 g(1, (NU + 127) / 128);
    mfma_gemm<true, true, false, false, false><<<g, blk, 0, stream>>>(x_user, WuT, 256, bu, (void*)x_all, 128, 128, NU, 128, 256); }
  { dim3 g(1, (NFOOD + 127) / 128);
    mfma_gemm<true, true, false, false, false><<<g, blk, 0, stream>>>(x_food, WfT, 512, bfo, (void*)(x_all + (size_t)NU * 128), 128, 128, NFOOD, 128, 512); }
  { dim3 g(1, (NING + 127) / 128);
    mfma_gemm<true, true, false, false, false><<<g, blk, 0, stream>>>(x_ing, WiT, 128, bi, (void*)(x_all + (size_t)(NU + NFOOD) * 128), 128, 128, NING, 128, 128); }
  { dim3 g(1, (NCAT + 127) / 128);
    mfma_gemm<true, true, false, false, false><<<g, blk, 0, stream>>>(x_cat, WcT, 64, bc, (void*)(x_all + (size_t)(NU + NFOOD + NING) * 128), 128, 128, NCAT, 128, 64); }
  { dim3 g(1, (NHAB + 127) / 128);
    mfma_gemm<true, true, false, false, false><<<g, blk, 0, stream>>>(x_hab, WhT, 64, bh, (void*)(x_all + (size_t)(NU + NFOOD + NING + NCAT) * 128), 128, 128, NHAB, 128, 64); }

  // ---- CSR build (XCD-partitioned) ----
  count_dst_xcd<<<2048, blk, 0, stream>>>(ei, cnt_dst);
  scan_block<<<NB1, SCAN_B, 0, stream>>>(cnt_dst, row_ptr, bsum, NNODES);
  scan_top<<<1, 512, 0, stream>>>(bsum, bofs, NB1);
  scan_apply<<<NB1, SCAN_B, 0, stream>>>(row_ptr, bofs, slot, NNODES);
  scatter_edges_xcd<<<2048, blk, 0, stream>>>(ei, et, slot, packed);

  if (pathA) {
    unsigned short* M9 = (unsigned short*)(ws + base);
    unsigned short* x1 = x_all;   // x_all dead after gather (copied into M9 root block)

    gather_means8<<<2048, blk, 0, stream>>>(row_ptr, packed, (const unsigned*)x_all,
                                            (unsigned*)M9, cnt8);
    // x1 = relu(M9 @ W1rT + b1)  (K=1152, bf16 out)
    { dim3 g(1, (NNODES + 127) / 128);
      mfma_gemm<false, true, false, true, false><<<g, blk, 0, stream>>>(M9, W1rT, 1152, b1, (void*)x1, 128, 128, NNODES, 128, 1152); }
    // h2 = x1 @ B2pad (store 18 cols)
    { dim3 g(1, (NNODES + 127) / 128);
      mfma_gemm<false, false, false, false, false><<<g, blk, 0, stream>>>(x1, B2pad, 128, nullptr, (void*)h2, 18, 18, NNODES, 128, 128); }
  } else {
    float* agg1 = (float*)(ws + base);
    unsigned short* M_blk = (unsigned short*)(ws + base + alignup((size_t)NNODES * 128 * 4));

    // agg1 = x_all @ root1 + b1
    { dim3 g(1, (NNODES + 127) / 128);
      mfma_gemm<false, false, false, false, false><<<g, blk, 0, stream>>>(x_all, rootT, 128, b1, (void*)agg1, 128, 128, NNODES, 128, 128); }
    for (int rb0 = 0; rb0 < NREL; rb0 += 4) {
      gather_means4<<<2048, blk, 0, stream>>>(row_ptr, packed, (const unsigned*)x_all,
                                              (unsigned*)M_blk, cnt8, rb0);
      dim3 g(1, (NNODES + 127) / 128);
      mfma_gemm<false, false, false, false, true><<<g, blk, 0, stream>>>(M_blk, W1rT + (size_t)rb0 * 128, 1152, nullptr, (void*)agg1, 128, 128, NNODES, 128, 512);
    }
    // h2 = relu(agg1) @ B2pad (store 18 cols)
    { dim3 g(1, (NNODES + 127) / 128);
      mfma_gemm<true, false, true, false, false><<<g, blk, 0, stream>>>(agg1, B2pad, 128, nullptr, (void*)h2, 18, 18, NNODES, 128, 128); }
  }

  fused_out<<<(NNODES * 4 + 255) / 256, blk, 0, stream>>>(row_ptr, packed, cnt8, h2, b2, (float*)d_out);
}

// Round 9
// 595.423 us; speedup vs baseline: 1.5134x; 1.2532x over previous
//
#include <hip/hip_runtime.h>
#include <hip/hip_bf16.h>
#include <math.h>

#define NU 50000
#define NFOOD 30000
#define NING 20000
#define NCAT 5000
#define NHAB 10000
#define NNODES 115000
#define NCHUNK 14375   // NNODES/8 (XCD dst partition)
#define NREL 8
#define NEDGE 1500000
#define SCAN_B 256

typedef __attribute__((ext_vector_type(8))) short short8;
typedef __attribute__((ext_vector_type(4))) float f32x4;

static inline size_t alignup(size_t x) { return (x + 255) & ~(size_t)255; }

__device__ inline float bf16_bits_to_f32(unsigned short u) {
  return __uint_as_float(((unsigned)u) << 16);
}
__device__ inline unsigned short f32_to_bf16_bits(float f) {
  unsigned u = __float_as_uint(f);
  unsigned r = u + 0x7fffu + ((u >> 16) & 1u);
  return (unsigned short)(r >> 16);
}

// ================= MFMA bf16 GEMM ==================================================
// C[M,N] = op(A)[M,K] @ B_T[N,K] (+bias). A row-major, lda==K. Bt [N][ldB] bf16.
// Tile 128x128, BK=64, 256 thr. LDS XOR swizzle byte ^= (row&7)<<4.
template <bool A_F32, bool OUT_BF16, bool RELU_OUT>
__global__ __launch_bounds__(256) void mfma_gemm(
    const void* __restrict__ Ain, const unsigned short* __restrict__ Bt, int ldB,
    const float* __restrict__ bias, void* __restrict__ Cv, int ldC, int Nstore,
    int M, int N, int K) {
  __shared__ char As[128 * 128];
  __shared__ char Bs[128 * 128];
  const int tid = threadIdx.x;
  const int lane = tid & 63;
  const int wv = tid >> 6;
  const int bm = blockIdx.y * 128;
  const int bn = blockIdx.x * 128;
  f32x4 acc[2][8] = {};

  for (int k0 = 0; k0 < K; k0 += 64) {
    if (A_F32) {
      const float* A = (const float*)Ain;
#pragma unroll
      for (int it = 0; it < 4; ++it) {
        int u = it * 256 + tid;
        int m = u >> 3, c = u & 7;
        int mg = bm + m; if (mg >= M) mg = M - 1;
        const float4* src = (const float4*)(A + (size_t)mg * K + k0 + c * 8);
        float4 lo4 = src[0], hi4 = src[1];
        unsigned q0 = f32_to_bf16_bits(lo4.x) | ((unsigned)f32_to_bf16_bits(lo4.y) << 16);
        unsigned q1 = f32_to_bf16_bits(lo4.z) | ((unsigned)f32_to_bf16_bits(lo4.w) << 16);
        unsigned q2 = f32_to_bf16_bits(hi4.x) | ((unsigned)f32_to_bf16_bits(hi4.y) << 16);
        unsigned q3 = f32_to_bf16_bits(hi4.z) | ((unsigned)f32_to_bf16_bits(hi4.w) << 16);
        int off = m * 128 + ((c * 16) ^ ((m & 7) << 4));
        *(int4*)(As + off) = make_int4(q0, q1, q2, q3);
      }
    } else {
      const unsigned short* A = (const unsigned short*)Ain;
#pragma unroll
      for (int it = 0; it < 4; ++it) {
        int u = it * 256 + tid;
        int m = u >> 3, c = u & 7;
        int mg = bm + m; if (mg >= M) mg = M - 1;
        int4 v = *(const int4*)((const char*)(A + (size_t)mg * K + k0) + c * 16);
        int off = m * 128 + ((c * 16) ^ ((m & 7) << 4));
        *(int4*)(As + off) = v;
      }
    }
#pragma unroll
    for (int it = 0; it < 4; ++it) {
      int u = it * 256 + tid;
      int n = u >> 3, c = u & 7;
      int4 v = *(const int4*)((const char*)(Bt + (size_t)(bn + n) * ldB + k0) + c * 16);
      int off = n * 128 + ((c * 16) ^ ((n & 7) << 4));
      *(int4*)(Bs + off) = v;
    }
    __syncthreads();
#pragma unroll
    for (int kk = 0; kk < 2; ++kk) {
      int kbyte = kk * 64 + ((lane >> 4) << 4);
      short8 af[2];
#pragma unroll
      for (int mi = 0; mi < 2; ++mi) {
        int m = wv * 32 + mi * 16 + (lane & 15);
        af[mi] = *(const short8*)(As + m * 128 + (kbyte ^ ((m & 7) << 4)));
      }
#pragma unroll
      for (int ni = 0; ni < 8; ++ni) {
        int n = ni * 16 + (lane & 15);
        short8 bf = *(const short8*)(Bs + n * 128 + (kbyte ^ ((n & 7) << 4)));
#pragma unroll
        for (int mi = 0; mi < 2; ++mi)
          acc[mi][ni] = __builtin_amdgcn_mfma_f32_16x16x32_bf16(af[mi], bf, acc[mi][ni], 0, 0, 0);
      }
    }
    __syncthreads();
  }
#pragma unroll
  for (int mi = 0; mi < 2; ++mi) {
#pragma unroll
    for (int r = 0; r < 4; ++r) {
      int row = bm + wv * 32 + mi * 16 + ((lane >> 4) << 2) + r;
      if (row < M) {
#pragma unroll
        for (int ni = 0; ni < 8; ++ni) {
          int col = bn + ni * 16 + (lane & 15);
          if (col < Nstore) {
            float v = acc[mi][ni][r] + (bias ? bias[col] : 0.f);
            if (RELU_OUT) v = fmaxf(v, 0.f);
            if (OUT_BF16)
              ((unsigned short*)Cv)[(size_t)row * ldC + col] = f32_to_bf16_bits(v);
            else
              ((float*)Cv)[(size_t)row * ldC + col] = v;
          }
        }
      }
    }
  }
}

// ================= weight repacks ==================================================
__global__ void build_Bt(const float* __restrict__ W, unsigned short* __restrict__ Wt,
                         int K, int N) {
  int idx = blockIdx.x * blockDim.x + threadIdx.x;
  if (idx >= N * K) return;
  int n = idx / K, k = idx - n * K;
  Wt[idx] = f32_to_bf16_bits(W[(size_t)k * N + n]);
}

// W1rT [128 f][1152]: cols t*128+k = W1[t][k][f] (t<8); cols 1024+k = root1[k][f]
__global__ void build_W1rT(const float* __restrict__ W1, const float* __restrict__ root1,
                           unsigned short* __restrict__ Wt) {
  int idx = blockIdx.x * blockDim.x + threadIdx.x;
  if (idx >= 128 * 1152) return;
  int f = idx / 1152, c = idx - f * 1152;
  float v;
  if (c < 1024) { int t = c >> 7, k = c & 127; v = W1[((size_t)t * 128 + k) * 128 + f]; }
  else { int k = c - 1024; v = root1[(size_t)k * 128 + f]; }
  Wt[idx] = f32_to_bf16_bits(v);
}

// B2pad [128][128] bf16: n<16: W2[n>>1][k][n&1]; 16<=n<18: root2[k][n-16]; else 0
__global__ void build_B2pad(const float* __restrict__ W2, const float* __restrict__ root2,
                            unsigned short* __restrict__ Bt) {
  int idx = blockIdx.x * blockDim.x + threadIdx.x;
  if (idx >= 128 * 128) return;
  int n = idx >> 7, k = idx & 127;
  float v = 0.f;
  if (n < 16) v = W2[((size_t)(n >> 1) * 128 + k) * 2 + (n & 1)];
  else if (n < 18) v = root2[(size_t)k * 2 + (n - 16)];
  Bt[idx] = f32_to_bf16_bits(v);
}

// ================= CSR build (XCD-partitioned by dst chunk) ========================
__global__ void count_dst_xcd(const int* __restrict__ ei, int* __restrict__ cnt_dst) {
  int cls = blockIdx.x & 7;
  unsigned lo = cls * NCHUNK, hi = lo + NCHUNK;
  int e = (blockIdx.x >> 3) * blockDim.x + threadIdx.x;
  int stride = (gridDim.x >> 3) * blockDim.x;
  for (; e < NEDGE; e += stride) {
    unsigned d = (unsigned)ei[NEDGE + e]; if (d >= NNODES) d = 0;
    if (d < lo || d >= hi) continue;
    atomicAdd(cnt_dst + d, 1);
  }
}

__global__ void scan_block(const int* __restrict__ in, int* __restrict__ out,
                           int* __restrict__ bsum, int n) {
  __shared__ int s[SCAN_B];
  int i = blockIdx.x * SCAN_B + threadIdx.x;
  int x = (i < n) ? in[i] : 0;
  s[threadIdx.x] = x;
  __syncthreads();
  for (int d = 1; d < SCAN_B; d <<= 1) {
    int v = (threadIdx.x >= d) ? s[threadIdx.x - d] : 0;
    __syncthreads();
    s[threadIdx.x] += v;
    __syncthreads();
  }
  if (i < n) out[i] = s[threadIdx.x] - x;
  if (threadIdx.x == SCAN_B - 1) bsum[blockIdx.x] = s[threadIdx.x];
}

__global__ void scan_top(int* __restrict__ bsum, int* __restrict__ bofs, int nb) {
  __shared__ int s[512];
  int x = (threadIdx.x < nb) ? bsum[threadIdx.x] : 0;
  s[threadIdx.x] = x;
  __syncthreads();
  for (int d = 1; d < 512; d <<= 1) {
    int v = (threadIdx.x >= d) ? s[threadIdx.x - d] : 0;
    __syncthreads();
    s[threadIdx.x] += v;
    __syncthreads();
  }
  if (threadIdx.x < nb) bofs[threadIdx.x] = s[threadIdx.x] - x;
}

__global__ void scan_apply(int* __restrict__ row_ptr, const int* __restrict__ bofs,
                           int* __restrict__ slot, int n) {
  int i = blockIdx.x * blockDim.x + threadIdx.x;
  if (i >= n) return;
  int v = row_ptr[i] + bofs[i / SCAN_B];
  row_ptr[i] = v;
  slot[i] = v;
}

__global__ void scatter_edges_xcd(const int* __restrict__ ei, const int* __restrict__ et,
                                  int* __restrict__ slot, unsigned* __restrict__ packed) {
  int cls = blockIdx.x & 7;
  unsigned lo = cls * NCHUNK, hi = lo + NCHUNK;
  int e = (blockIdx.x >> 3) * blockDim.x + threadIdx.x;
  int stride = (gridDim.x >> 3) * blockDim.x;
  for (; e < NEDGE; e += stride) {
    unsigned d = (unsigned)ei[NEDGE + e]; if (d >= NNODES) d = 0;
    if (d < lo || d >= hi) continue;
    unsigned s = (unsigned)ei[e];  if (s >= NNODES) s = 0;
    unsigned t = (unsigned)et[e];  if (t >= NREL)  t = 0;
    int pos = atomicAdd(slot + d, 1);
    packed[pos] = (t << 17) | s;
  }
}

// ============ layer-1 gather-means, all 8 relations, dst chunk [d0,d1) =============
// M9[d-d0] = [8 x 128 means | x_all[d]] bf16 (1152 cols); cnt8[d][t] u16 counts.
__global__ __launch_bounds__(256) void gather_means8(
    const int* __restrict__ row_ptr, const unsigned* __restrict__ packed,
    const unsigned* __restrict__ xu, unsigned* __restrict__ M9,
    unsigned short* __restrict__ cnt8, int d0, int d1) {
  int lane = threadIdx.x & 63;
  int wid = (blockIdx.x * blockDim.x + threadIdx.x) >> 6;
  int nw = (gridDim.x * blockDim.x) >> 6;
  for (int d = d0 + wid; d < d1; d += nw) {
    int beg = row_ptr[d];
    int end = (d == NNODES - 1) ? NEDGE : row_ptr[d + 1];
    float a0[8], a1[8];
    int c[8];
#pragma unroll
    for (int q = 0; q < 8; ++q) { a0[q] = 0.f; a1[q] = 0.f; c[q] = 0; }
    for (int e = beg; e < end; ++e) {
      unsigned p = packed[e];
      unsigned t = p >> 17;
      unsigned u = xu[(size_t)(p & 0x1FFFFu) * 64 + lane];
      float lo = bf16_bits_to_f32((unsigned short)(u & 0xffffu));
      float hi = bf16_bits_to_f32((unsigned short)(u >> 16));
#pragma unroll
      for (int q = 0; q < 8; ++q) {
        bool m = (t == (unsigned)q);
        a0[q] += m ? lo : 0.f;
        a1[q] += m ? hi : 0.f;
        c[q] += m ? 1 : 0;
      }
    }
    unsigned* rowp = M9 + (size_t)(d - d0) * 576;   // 1152 bf16 = 576 u32
#pragma unroll
    for (int q = 0; q < 8; ++q) {
      float w = 1.0f / (float)(c[q] > 0 ? c[q] : 1);
      rowp[q * 64 + lane] = f32_to_bf16_bits(a0[q] * w) |
                            ((unsigned)f32_to_bf16_bits(a1[q] * w) << 16);
    }
    rowp[512 + lane] = xu[(size_t)d * 64 + lane];   // root block = x_all row
    if (lane == 0) {
      uint4 cw;
      cw.x = (unsigned)c[0] | ((unsigned)c[1] << 16);
      cw.y = (unsigned)c[2] | ((unsigned)c[3] << 16);
      cw.z = (unsigned)c[4] | ((unsigned)c[5] << 16);
      cw.w = (unsigned)c[6] | ((unsigned)c[7] << 16);
      *(uint4*)(cnt8 + (size_t)d * 8) = cw;
    }
  }
}

// ============ layer-2 aggregation + log_softmax (4 lanes per dst, cnt8-based) ======
__global__ void fused_out(const int* __restrict__ row_ptr, const unsigned* __restrict__ packed,
                          const unsigned short* __restrict__ cnt8,
                          const float* __restrict__ h2, const float* __restrict__ b2,
                          float* __restrict__ out) {
  int gt = blockIdx.x * blockDim.x + threadIdx.x;
  int d = gt >> 2;
  int l4 = gt & 3;
  if (d >= NNODES) return;
  int beg = row_ptr[d];
  int end = (d == NNODES - 1) ? NEDGE : row_ptr[d + 1];
  uint4 cw = *(const uint4*)(cnt8 + (size_t)d * 8);
  float wr[8];
  wr[0] = 1.0f / (float)((cw.x & 0xffffu) ? (cw.x & 0xffffu) : 1u);
  wr[1] = 1.0f / (float)((cw.x >> 16) ? (cw.x >> 16) : 1u);
  wr[2] = 1.0f / (float)((cw.y & 0xffffu) ? (cw.y & 0xffffu) : 1u);
  wr[3] = 1.0f / (float)((cw.y >> 16) ? (cw.y >> 16) : 1u);
  wr[4] = 1.0f / (float)((cw.z & 0xffffu) ? (cw.z & 0xffffu) : 1u);
  wr[5] = 1.0f / (float)((cw.z >> 16) ? (cw.z >> 16) : 1u);
  wr[6] = 1.0f / (float)((cw.w & 0xffffu) ? (cw.w & 0xffffu) : 1u);
  wr[7] = 1.0f / (float)((cw.w >> 16) ? (cw.w >> 16) : 1u);
  float z0 = 0.f, z1 = 0.f;
  for (int e = beg + l4; e < end; e += 4) {
    unsigned p = packed[e];
    unsigned s = p & 0x1FFFFu;
    unsigned t = p >> 17;
    float w = 1.f;
#pragma unroll
    for (int q = 0; q < 8; ++q) w = (t == (unsigned)q) ? wr[q] : w;
    z0 = fmaf(h2[(size_t)s * 18 + t * 2], w, z0);
    z1 = fmaf(h2[(size_t)s * 18 + t * 2 + 1], w, z1);
  }
  z0 += __shfl_xor(z0, 1, 4); z0 += __shfl_xor(z0, 2, 4);
  z1 += __shfl_xor(z1, 1, 4); z1 += __shfl_xor(z1, 2, 4);
  if (l4 == 0) {
    z0 += h2[(size_t)d * 18 + 16] + b2[0];
    z1 += h2[(size_t)d * 18 + 17] + b2[1];
    float m = fmaxf(z0, z1);
    float l = m + logf(expf(z0 - m) + expf(z1 - m));
    out[(size_t)d * 2 + 0] = z0 - l;
    out[(size_t)d * 2 + 1] = z1 - l;
  }
}

__global__ void fill_sentinel(float* __restrict__ out, int n, float v) {
  int i = blockIdx.x * blockDim.x + threadIdx.x;
  if (i < n) out[i] = v;
}

// ===================================================================================
extern "C" void kernel_launch(void* const* d_in, const int* in_sizes, int n_in,
                              void* d_out, int out_size, void* d_ws, size_t ws_size,
                              hipStream_t stream) {
  const float* x_user = (const float*)d_in[0];
  const float* x_food = (const float*)d_in[1];
  const float* x_ing  = (const float*)d_in[2];
  const float* x_cat  = (const float*)d_in[3];
  const float* x_hab  = (const float*)d_in[4];
  const float* Wu = (const float*)d_in[5];  const float* bu  = (const float*)d_in[6];
  const float* Wf = (const float*)d_in[7];  const float* bfo = (const float*)d_in[8];
  const float* Wi = (const float*)d_in[9];  const float* bi  = (const float*)d_in[10];
  const float* Wc = (const float*)d_in[11]; const float* bc  = (const float*)d_in[12];
  const float* Wh = (const float*)d_in[13]; const float* bh  = (const float*)d_in[14];
  const float* W1 = (const float*)d_in[15]; const float* root1 = (const float*)d_in[16];
  const float* b1 = (const float*)d_in[17];
  const float* W2 = (const float*)d_in[18]; const float* root2 = (const float*)d_in[19];
  const float* b2 = (const float*)d_in[20];
  const int* ei = (const int*)d_in[21];
  const int* et = (const int*)d_in[22];
  (void)in_sizes; (void)n_in;

  dim3 blk(256);
  const int NB1 = (NNODES + SCAN_B - 1) / SCAN_B;   // 450

  // ---- base layout ----
  char* ws = (char*)d_ws;
  size_t off = 0;
  unsigned short* x_all = (unsigned short*)(ws + off); off += alignup((size_t)NNODES * 128 * 2);
  unsigned short* x1    = (unsigned short*)(ws + off); off += alignup((size_t)NNODES * 128 * 2);
  int* cnt_dst = (int*)(ws + off);       off += alignup((size_t)NNODES * 4);
  int* row_ptr = (int*)(ws + off);       off += alignup((size_t)NNODES * 4);
  int* slot = (int*)(ws + off);          off += alignup((size_t)NNODES * 4);
  unsigned* packed = (unsigned*)(ws + off); off += alignup((size_t)NEDGE * 4);
  int* bsum = (int*)(ws + off);          off += alignup((size_t)512 * 4);
  int* bofs = (int*)(ws + off);          off += alignup((size_t)512 * 4);
  unsigned short* WuT = (unsigned short*)(ws + off); off += alignup((size_t)128 * 256 * 2);
  unsigned short* WfT = (unsigned short*)(ws + off); off += alignup((size_t)128 * 512 * 2);
  unsigned short* WiT = (unsigned short*)(ws + off); off += alignup((size_t)128 * 128 * 2);
  unsigned short* WcT = (unsigned short*)(ws + off); off += alignup((size_t)128 * 64 * 2);
  unsigned short* WhT = (unsigned short*)(ws + off); off += alignup((size_t)128 * 64 * 2);
  unsigned short* W1rT = (unsigned short*)(ws + off); off += alignup((size_t)128 * 1152 * 2);
  unsigned short* B2pad = (unsigned short*)(ws + off); off += alignup((size_t)128 * 128 * 2);
  unsigned short* cnt8 = (unsigned short*)(ws + off); off += alignup((size_t)NNODES * 8 * 2);
  float* h2 = (float*)(ws + off);        off += alignup((size_t)NNODES * 18 * 4);
  size_t base = off;

  // pick smallest chunk count whose M9 half-buffer fits
  int NCH = 0;
  for (int cand = 2; cand <= 16; cand <<= 1) {
    size_t ch = ((size_t)NNODES + cand - 1) / cand;
    if (base + alignup(ch * 1152 * 2) <= ws_size) { NCH = cand; break; }
  }
  if (NCH == 0) {
    fill_sentinel<<<(out_size + 255) / 256, blk, 0, stream>>>((float*)d_out, out_size, -777.0f);
    return;
  }
  unsigned short* M9 = (unsigned short*)(ws + base);
  const int CH = (NNODES + NCH - 1) / NCH;

  hipMemsetAsync(cnt_dst, 0, (size_t)NNODES * 4, stream);

  // ---- weight repacks ----
  build_Bt<<<(128 * 256 + 255) / 256, blk, 0, stream>>>(Wu, WuT, 256, 128);
  build_Bt<<<(128 * 512 + 255) / 256, blk, 0, stream>>>(Wf, WfT, 512, 128);
  build_Bt<<<(128 * 128 + 255) / 256, blk, 0, stream>>>(Wi, WiT, 128, 128);
  build_Bt<<<(128 * 64 + 255) / 256, blk, 0, stream>>>(Wc, WcT, 64, 128);
  build_Bt<<<(128 * 64 + 255) / 256, blk, 0, stream>>>(Wh, WhT, 64, 128);
  build_W1rT<<<(128 * 1152 + 255) / 256, blk, 0, stream>>>(W1, root1, W1rT);
  build_B2pad<<<(128 * 128 + 255) / 256, blk, 0, stream>>>(W2, root2, B2pad);

  // ---- projections -> x_all (bf16) ----
  { dim3 g(1, (NU + 127) / 128);
    mfma_gemm<true, true, false><<<g, blk, 0, stream>>>(x_user, WuT, 256, bu, (void*)x_all, 128, 128, NU, 128, 256); }
  { dim3 g(1, (NFOOD + 127) / 128);
    mfma_gemm<true, true, false><<<g, blk, 0, stream>>>(x_food, WfT, 512, bfo, (void*)(x_all + (size_t)NU * 128), 128, 128, NFOOD, 128, 512); }
  { dim3 g(1, (NING + 127) / 128);
    mfma_gemm<true, true, false><<<g, blk, 0, stream>>>(x_ing, WiT, 128, bi, (void*)(x_all + (size_t)(NU + NFOOD) * 128), 128, 128, NING, 128, 128); }
  { dim3 g(1, (NCAT + 127) / 128);
    mfma_gemm<true, true, false><<<g, blk, 0, stream>>>(x_cat, WcT, 64, bc, (void*)(x_all + (size_t)(NU + NFOOD + NING) * 128), 128, 128, NCAT, 128, 64); }
  { dim3 g(1, (NHAB + 127) / 128);
    mfma_gemm<true, true, false><<<g, blk, 0, stream>>>(x_hab, WhT, 64, bh, (void*)(x_all + (size_t)(NU + NFOOD + NING + NCAT) * 128), 128, 128, NHAB, 128, 64); }

  // ---- CSR build (XCD-partitioned) ----
  count_dst_xcd<<<2048, blk, 0, stream>>>(ei, cnt_dst);
  scan_block<<<NB1, SCAN_B, 0, stream>>>(cnt_dst, row_ptr, bsum, NNODES);
  scan_top<<<1, 512, 0, stream>>>(bsum, bofs, NB1);
  scan_apply<<<NB1, SCAN_B, 0, stream>>>(row_ptr, bofs, slot, NNODES);
  scatter_edges_xcd<<<2048, blk, 0, stream>>>(ei, et, slot, packed);

  // ---- layer 1: per dst-chunk, single-pass gather + K=1152 GEMM -> x1 ----
  for (int c = 0; c < NCH; ++c) {
    int d0 = c * CH;
    int d1 = (d0 + CH < NNODES) ? d0 + CH : NNODES;
    int Mc = d1 - d0;
    gather_means8<<<2048, blk, 0, stream>>>(row_ptr, packed, (const unsigned*)x_all,
                                            (unsigned*)M9, cnt8, d0, d1);
    dim3 g(1, (Mc + 127) / 128);
    mfma_gemm<false, true, true><<<g, blk, 0, stream>>>(M9, W1rT, 1152, b1,
        (void*)(x1 + (size_t)d0 * 128), 128, 128, Mc, 128, 1152);
  }

  // ---- layer 2: h2 = x1 @ B2pad (store 18 cols) ----
  { dim3 g(1, (NNODES + 127) / 128);
    mfma_gemm<false, false, false><<<g, blk, 0, stream>>>(x1, B2pad, 128, nullptr, (void*)h2, 18, 18, NNODES, 128, 128); }

  fused_out<<<(NNODES * 4 + 255) / 256, blk, 0, stream>>>(row_ptr, packed, cnt8, h2, b2, (float*)d_out);
}

// Round 10
// 553.786 us; speedup vs baseline: 1.6271x; 1.0752x over previous
//
#include <hip/hip_runtime.h>
#include <hip/hip_bf16.h>
#include <math.h>

#define NU 50000
#define NFOOD 30000
#define NING 20000
#define NCAT 5000
#define NHAB 10000
#define NNODES 115000
#define NCHUNK 14375   // NNODES/8 (XCD dst partition)
#define NREL 8
#define NSEG (NNODES * NREL)   // 920000
#define NEDGE 1500000
#define SCAN_B 256

typedef __attribute__((ext_vector_type(8))) short short8;
typedef __attribute__((ext_vector_type(4))) float f32x4;

static inline size_t alignup(size_t x) { return (x + 255) & ~(size_t)255; }

__device__ inline float bf16_bits_to_f32(unsigned short u) {
  return __uint_as_float(((unsigned)u) << 16);
}
__device__ inline unsigned short f32_to_bf16_bits(float f) {
  unsigned u = __float_as_uint(f);
  unsigned r = u + 0x7fffu + ((u >> 16) & 1u);
  return (unsigned short)(r >> 16);
}

// ================= MFMA bf16 GEMM (generic) ========================================
// C[M,N] = op(A)[M,K] @ B_T[N,K] (+bias). A row-major, lda==K. Bt [N][ldB] bf16.
// Tile 128x128, BK=64, 256 thr. LDS XOR swizzle byte ^= (row&7)<<4.
template <bool A_F32, bool OUT_BF16, bool RELU_OUT>
__global__ __launch_bounds__(256) void mfma_gemm(
    const void* __restrict__ Ain, const unsigned short* __restrict__ Bt, int ldB,
    const float* __restrict__ bias, void* __restrict__ Cv, int ldC, int Nstore,
    int M, int N, int K) {
  __shared__ char As[128 * 128];
  __shared__ char Bs[128 * 128];
  const int tid = threadIdx.x;
  const int lane = tid & 63;
  const int wv = tid >> 6;
  const int bm = blockIdx.y * 128;
  const int bn = blockIdx.x * 128;
  f32x4 acc[2][8] = {};

  for (int k0 = 0; k0 < K; k0 += 64) {
    if (A_F32) {
      const float* A = (const float*)Ain;
#pragma unroll
      for (int it = 0; it < 4; ++it) {
        int u = it * 256 + tid;
        int m = u >> 3, c = u & 7;
        int mg = bm + m; if (mg >= M) mg = M - 1;
        const float4* src = (const float4*)(A + (size_t)mg * K + k0 + c * 8);
        float4 lo4 = src[0], hi4 = src[1];
        unsigned q0 = f32_to_bf16_bits(lo4.x) | ((unsigned)f32_to_bf16_bits(lo4.y) << 16);
        unsigned q1 = f32_to_bf16_bits(lo4.z) | ((unsigned)f32_to_bf16_bits(lo4.w) << 16);
        unsigned q2 = f32_to_bf16_bits(hi4.x) | ((unsigned)f32_to_bf16_bits(hi4.y) << 16);
        unsigned q3 = f32_to_bf16_bits(hi4.z) | ((unsigned)f32_to_bf16_bits(hi4.w) << 16);
        int off = m * 128 + ((c * 16) ^ ((m & 7) << 4));
        *(int4*)(As + off) = make_int4(q0, q1, q2, q3);
      }
    } else {
      const unsigned short* A = (const unsigned short*)Ain;
#pragma unroll
      for (int it = 0; it < 4; ++it) {
        int u = it * 256 + tid;
        int m = u >> 3, c = u & 7;
        int mg = bm + m; if (mg >= M) mg = M - 1;
        int4 v = *(const int4*)((const char*)(A + (size_t)mg * K + k0) + c * 16);
        int off = m * 128 + ((c * 16) ^ ((m & 7) << 4));
        *(int4*)(As + off) = v;
      }
    }
#pragma unroll
    for (int it = 0; it < 4; ++it) {
      int u = it * 256 + tid;
      int n = u >> 3, c = u & 7;
      int4 v = *(const int4*)((const char*)(Bt + (size_t)(bn + n) * ldB + k0) + c * 16);
      int off = n * 128 + ((c * 16) ^ ((n & 7) << 4));
      *(int4*)(Bs + off) = v;
    }
    __syncthreads();
#pragma unroll
    for (int kk = 0; kk < 2; ++kk) {
      int kbyte = kk * 64 + ((lane >> 4) << 4);
      short8 af[2];
#pragma unroll
      for (int mi = 0; mi < 2; ++mi) {
        int m = wv * 32 + mi * 16 + (lane & 15);
        af[mi] = *(const short8*)(As + m * 128 + (kbyte ^ ((m & 7) << 4)));
      }
#pragma unroll
      for (int ni = 0; ni < 8; ++ni) {
        int n = ni * 16 + (lane & 15);
        short8 bf = *(const short8*)(Bs + n * 128 + (kbyte ^ ((n & 7) << 4)));
#pragma unroll
        for (int mi = 0; mi < 2; ++mi)
          acc[mi][ni] = __builtin_amdgcn_mfma_f32_16x16x32_bf16(af[mi], bf, acc[mi][ni], 0, 0, 0);
      }
    }
    __syncthreads();
  }
#pragma unroll
  for (int mi = 0; mi < 2; ++mi) {
#pragma unroll
    for (int r = 0; r < 4; ++r) {
      int row = bm + wv * 32 + mi * 16 + ((lane >> 4) << 2) + r;
      if (row < M) {
#pragma unroll
        for (int ni = 0; ni < 8; ++ni) {
          int col = bn + ni * 16 + (lane & 15);
          if (col < Nstore) {
            float v = acc[mi][ni][r] + (bias ? bias[col] : 0.f);
            if (RELU_OUT) v = fmaxf(v, 0.f);
            if (OUT_BF16)
              ((unsigned short*)Cv)[(size_t)row * ldC + col] = f32_to_bf16_bits(v);
            else
              ((float*)Cv)[(size_t)row * ldC + col] = v;
          }
        }
      }
    }
  }
}

// ================= layer-1 GEMM: A = [M9 (1024 cols) | x_all rows] =================
// x1[d0+m] = relu(concat(M9[m], x_all[d0+m]) @ W1rT^T + b1), K=1152, N=128, bf16 out.
__global__ __launch_bounds__(256) void l1_gemm(
    const unsigned short* __restrict__ M9, const unsigned short* __restrict__ xall,
    const unsigned short* __restrict__ W1rT, const float* __restrict__ b1,
    unsigned short* __restrict__ x1, int d0, int Mc) {
  __shared__ char As[128 * 128];
  __shared__ char Bs[128 * 128];
  const int tid = threadIdx.x;
  const int lane = tid & 63;
  const int wv = tid >> 6;
  const int bm = blockIdx.y * 128;
  f32x4 acc[2][8] = {};

  for (int k0 = 0; k0 < 1152; k0 += 64) {
#pragma unroll
    for (int it = 0; it < 4; ++it) {
      int u = it * 256 + tid;
      int m = u >> 3, c = u & 7;
      int mg = bm + m; if (mg >= Mc) mg = Mc - 1;
      const char* src;
      if (k0 < 1024) src = (const char*)(M9 + (size_t)mg * 1024 + k0) + c * 16;
      else src = (const char*)(xall + (size_t)(d0 + mg) * 128 + (k0 - 1024)) + c * 16;
      int4 v = *(const int4*)src;
      int off = m * 128 + ((c * 16) ^ ((m & 7) << 4));
      *(int4*)(As + off) = v;
    }
#pragma unroll
    for (int it = 0; it < 4; ++it) {
      int u = it * 256 + tid;
      int n = u >> 3, c = u & 7;
      int4 v = *(const int4*)((const char*)(W1rT + (size_t)n * 1152 + k0) + c * 16);
      int off = n * 128 + ((c * 16) ^ ((n & 7) << 4));
      *(int4*)(Bs + off) = v;
    }
    __syncthreads();
#pragma unroll
    for (int kk = 0; kk < 2; ++kk) {
      int kbyte = kk * 64 + ((lane >> 4) << 4);
      short8 af[2];
#pragma unroll
      for (int mi = 0; mi < 2; ++mi) {
        int m = wv * 32 + mi * 16 + (lane & 15);
        af[mi] = *(const short8*)(As + m * 128 + (kbyte ^ ((m & 7) << 4)));
      }
#pragma unroll
      for (int ni = 0; ni < 8; ++ni) {
        int n = ni * 16 + (lane & 15);
        short8 bf = *(const short8*)(Bs + n * 128 + (kbyte ^ ((n & 7) << 4)));
#pragma unroll
        for (int mi = 0; mi < 2; ++mi)
          acc[mi][ni] = __builtin_amdgcn_mfma_f32_16x16x32_bf16(af[mi], bf, acc[mi][ni], 0, 0, 0);
      }
    }
    __syncthreads();
  }
#pragma unroll
  for (int mi = 0; mi < 2; ++mi) {
#pragma unroll
    for (int r = 0; r < 4; ++r) {
      int row = bm + wv * 32 + mi * 16 + ((lane >> 4) << 2) + r;
      if (row < Mc) {
#pragma unroll
        for (int ni = 0; ni < 8; ++ni) {
          int col = ni * 16 + (lane & 15);
          float v = fmaxf(acc[mi][ni][r] + b1[col], 0.f);
          x1[(size_t)(d0 + row) * 128 + col] = f32_to_bf16_bits(v);
        }
      }
    }
  }
}

// ================= weight repacks ==================================================
__global__ void build_Bt(const float* __restrict__ W, unsigned short* __restrict__ Wt,
                         int K, int N) {
  int idx = blockIdx.x * blockDim.x + threadIdx.x;
  if (idx >= N * K) return;
  int n = idx / K, k = idx - n * K;
  Wt[idx] = f32_to_bf16_bits(W[(size_t)k * N + n]);
}

// W1rT [128 f][1152]: cols t*128+k = W1[t][k][f] (t<8); cols 1024+k = root1[k][f]
__global__ void build_W1rT(const float* __restrict__ W1, const float* __restrict__ root1,
                           unsigned short* __restrict__ Wt) {
  int idx = blockIdx.x * blockDim.x + threadIdx.x;
  if (idx >= 128 * 1152) return;
  int f = idx / 1152, c = idx - f * 1152;
  float v;
  if (c < 1024) { int t = c >> 7, k = c & 127; v = W1[((size_t)t * 128 + k) * 128 + f]; }
  else { int k = c - 1024; v = root1[(size_t)k * 128 + f]; }
  Wt[idx] = f32_to_bf16_bits(v);
}

// B2pad [128][128] bf16: n<16: W2[n>>1][k][n&1]; 16<=n<18: root2[k][n-16]; else 0
__global__ void build_B2pad(const float* __restrict__ W2, const float* __restrict__ root2,
                            unsigned short* __restrict__ Bt) {
  int idx = blockIdx.x * blockDim.x + threadIdx.x;
  if (idx >= 128 * 128) return;
  int n = idx >> 7, k = idx & 127;
  float v = 0.f;
  if (n < 16) v = W2[((size_t)(n >> 1) * 128 + k) * 2 + (n & 1)];
  else if (n < 18) v = root2[(size_t)k * 2 + (n - 16)];
  Bt[idx] = f32_to_bf16_bits(v);
}

// ========== CSR build keyed by (dst, rel), XCD-partitioned by dst chunk ===========
__global__ void count_dt_xcd(const int* __restrict__ ei, const int* __restrict__ et,
                             int* __restrict__ cnt_dt) {
  int cls = blockIdx.x & 7;
  unsigned lo = cls * NCHUNK, hi = lo + NCHUNK;
  int e = (blockIdx.x >> 3) * blockDim.x + threadIdx.x;
  int stride = (gridDim.x >> 3) * blockDim.x;
  for (; e < NEDGE; e += stride) {
    unsigned d = (unsigned)ei[NEDGE + e]; if (d >= NNODES) d = 0;
    if (d < lo || d >= hi) continue;
    unsigned t = (unsigned)et[e]; if (t >= NREL) t = 0;
    atomicAdd(cnt_dt + d * NREL + t, 1);
  }
}

__global__ void scan_block(const int* __restrict__ in, int* __restrict__ out,
                           int* __restrict__ bsum, int n) {
  __shared__ int s[SCAN_B];
  int i = blockIdx.x * SCAN_B + threadIdx.x;
  int x = (i < n) ? in[i] : 0;
  s[threadIdx.x] = x;
  __syncthreads();
  for (int d = 1; d < SCAN_B; d <<= 1) {
    int v = (threadIdx.x >= d) ? s[threadIdx.x - d] : 0;
    __syncthreads();
    s[threadIdx.x] += v;
    __syncthreads();
  }
  if (i < n) out[i] = s[threadIdx.x] - x;
  if (threadIdx.x == SCAN_B - 1) bsum[blockIdx.x] = s[threadIdx.x];
}

__global__ void scan_top(int* __restrict__ bsum, int* __restrict__ bofs, int nb) {
  __shared__ int s[512];
  int x = (threadIdx.x < nb) ? bsum[threadIdx.x] : 0;
  s[threadIdx.x] = x;
  __syncthreads();
  for (int d = 1; d < 512; d <<= 1) {
    int v = (threadIdx.x >= d) ? s[threadIdx.x - d] : 0;
    __syncthreads();
    s[threadIdx.x] += v;
    __syncthreads();
  }
  if (threadIdx.x < nb) bofs[threadIdx.x] = s[threadIdx.x] - x;
}

// rp2[i] += lvl1[i>>8] + lvl2[i>>16]; slot[i] = rp2[i]
__global__ void scan_apply3(int* __restrict__ rp2, const int* __restrict__ lvl1,
                            const int* __restrict__ lvl2, int* __restrict__ slot, int n) {
  int i = blockIdx.x * blockDim.x + threadIdx.x;
  if (i >= n) return;
  int v = rp2[i] + lvl1[i >> 8] + lvl2[i >> 16];
  rp2[i] = v;
  slot[i] = v;
}

__global__ void scatter_edges_xcd(const int* __restrict__ ei, const int* __restrict__ et,
                                  int* __restrict__ slot, unsigned* __restrict__ packed) {
  int cls = blockIdx.x & 7;
  unsigned lo = cls * NCHUNK, hi = lo + NCHUNK;
  int e = (blockIdx.x >> 3) * blockDim.x + threadIdx.x;
  int stride = (gridDim.x >> 3) * blockDim.x;
  for (; e < NEDGE; e += stride) {
    unsigned d = (unsigned)ei[NEDGE + e]; if (d >= NNODES) d = 0;
    if (d < lo || d >= hi) continue;
    unsigned s = (unsigned)ei[e];  if (s >= NNODES) s = 0;
    unsigned t = (unsigned)et[e];  if (t >= NREL)  t = 0;
    int pos = atomicAdd(slot + d * NREL + t, 1);
    packed[pos] = s;
  }
}

// ===== layer-1 gather-means: relation-sorted sub-segments, dst chunk [d0,d1) ======
// M9[d-d0] = 8 x 128 relation means (1024 cols bf16).
__global__ __launch_bounds__(256) void gather_means8(
    const int* __restrict__ rp2, const unsigned* __restrict__ packed,
    const unsigned* __restrict__ xu, unsigned* __restrict__ M9, int d0, int d1) {
  int lane = threadIdx.x & 63;
  int wid = (blockIdx.x * blockDim.x + threadIdx.x) >> 6;
  int nw = (gridDim.x * blockDim.x) >> 6;
  for (int d = d0 + wid; d < d1; d += nw) {
    int base_i = d * NREL;
    unsigned* rowp = M9 + (size_t)(d - d0) * 512;   // 1024 bf16 = 512 u32
    int beg = rp2[base_i];
#pragma unroll
    for (int t = 0; t < 8; ++t) {
      int i = base_i + t;
      int end = (i == NSEG - 1) ? NEDGE : rp2[i + 1];
      float a0 = 0.f, a1 = 0.f;
      for (int e = beg; e < end; ++e) {
        unsigned u = xu[(size_t)packed[e] * 64 + lane];
        a0 += bf16_bits_to_f32((unsigned short)(u & 0xffffu));
        a1 += bf16_bits_to_f32((unsigned short)(u >> 16));
      }
      int c = end - beg;
      float w = 1.0f / (float)(c > 0 ? c : 1);
      rowp[t * 64 + lane] = f32_to_bf16_bits(a0 * w) |
                            ((unsigned)f32_to_bf16_bits(a1 * w) << 16);
      beg = end;
    }
  }
}

// ===== layer-2 aggregation + log_softmax (4 lanes/dst; lane owns 2 relations) ======
__global__ void fused_out(const int* __restrict__ rp2, const unsigned* __restrict__ packed,
                          const float* __restrict__ h2, const float* __restrict__ b2,
                          float* __restrict__ out) {
  int gt = blockIdx.x * blockDim.x + threadIdx.x;
  int d = gt >> 2;
  int l4 = gt & 3;
  if (d >= NNODES) return;
  float z0 = 0.f, z1 = 0.f;
#pragma unroll
  for (int k = 0; k < 2; ++k) {
    int t = l4 * 2 + k;
    int i = d * NREL + t;
    int beg = rp2[i];
    int end = (i == NSEG - 1) ? NEDGE : rp2[i + 1];
    float s0 = 0.f, s1 = 0.f;
    for (int e = beg; e < end; ++e) {
      unsigned s = packed[e];
      s0 += h2[(size_t)s * 18 + t * 2];
      s1 += h2[(size_t)s * 18 + t * 2 + 1];
    }
    int c = end - beg;
    float w = 1.0f / (float)(c > 0 ? c : 1);
    z0 += s0 * w;
    z1 += s1 * w;
  }
  z0 += __shfl_xor(z0, 1, 4); z0 += __shfl_xor(z0, 2, 4);
  z1 += __shfl_xor(z1, 1, 4); z1 += __shfl_xor(z1, 2, 4);
  if (l4 == 0) {
    z0 += h2[(size_t)d * 18 + 16] + b2[0];
    z1 += h2[(size_t)d * 18 + 17] + b2[1];
    float m = fmaxf(z0, z1);
    float l = m + logf(expf(z0 - m) + expf(z1 - m));
    out[(size_t)d * 2 + 0] = z0 - l;
    out[(size_t)d * 2 + 1] = z1 - l;
  }
}

__global__ void fill_sentinel(float* __restrict__ out, int n, float v) {
  int i = blockIdx.x * blockDim.x + threadIdx.x;
  if (i < n) out[i] = v;
}

// ===================================================================================
extern "C" void kernel_launch(void* const* d_in, const int* in_sizes, int n_in,
                              void* d_out, int out_size, void* d_ws, size_t ws_size,
                              hipStream_t stream) {
  const float* x_user = (const float*)d_in[0];
  const float* x_food = (const float*)d_in[1];
  const float* x_ing  = (const float*)d_in[2];
  const float* x_cat  = (const float*)d_in[3];
  const float* x_hab  = (const float*)d_in[4];
  const float* Wu = (const float*)d_in[5];  const float* bu  = (const float*)d_in[6];
  const float* Wf = (const float*)d_in[7];  const float* bfo = (const float*)d_in[8];
  const float* Wi = (const float*)d_in[9];  const float* bi  = (const float*)d_in[10];
  const float* Wc = (const float*)d_in[11]; const float* bc  = (const float*)d_in[12];
  const float* Wh = (const float*)d_in[13]; const float* bh  = (const float*)d_in[14];
  const float* W1 = (const float*)d_in[15]; const float* root1 = (const float*)d_in[16];
  const float* b1 = (const float*)d_in[17];
  const float* W2 = (const float*)d_in[18]; const float* root2 = (const float*)d_in[19];
  const float* b2 = (const float*)d_in[20];
  const int* ei = (const int*)d_in[21];
  const int* et = (const int*)d_in[22];
  (void)in_sizes; (void)n_in;

  dim3 blk(256);
  const int NB_A = (NSEG + SCAN_B - 1) / SCAN_B;   // 3594
  const int NB_B = (NB_A + SCAN_B - 1) / SCAN_B;   // 15

  // ---- base layout (~86 MB) ----
  char* ws = (char*)d_ws;
  size_t off = 0;
  unsigned short* x_all = (unsigned short*)(ws + off); off += alignup((size_t)NNODES * 128 * 2);
  unsigned short* x1    = (unsigned short*)(ws + off); off += alignup((size_t)NNODES * 128 * 2);
  int* cnt_dt = (int*)(ws + off);        off += alignup((size_t)NSEG * 4);
  int* rp2 = (int*)(ws + off);           off += alignup((size_t)NSEG * 4);
  int* slot = (int*)(ws + off);          off += alignup((size_t)NSEG * 4);
  unsigned* packed = (unsigned*)(ws + off); off += alignup((size_t)NEDGE * 4);
  int* bsumA = (int*)(ws + off);         off += alignup((size_t)4096 * 4);
  int* bsumAs = (int*)(ws + off);        off += alignup((size_t)4096 * 4);
  int* bsumB = (int*)(ws + off);         off += alignup((size_t)64 * 4);
  int* bofsB = (int*)(ws + off);         off += alignup((size_t)64 * 4);
  unsigned short* WuT = (unsigned short*)(ws + off); off += alignup((size_t)128 * 256 * 2);
  unsigned short* WfT = (unsigned short*)(ws + off); off += alignup((size_t)128 * 512 * 2);
  unsigned short* WiT = (unsigned short*)(ws + off); off += alignup((size_t)128 * 128 * 2);
  unsigned short* WcT = (unsigned short*)(ws + off); off += alignup((size_t)128 * 64 * 2);
  unsigned short* WhT = (unsigned short*)(ws + off); off += alignup((size_t)128 * 64 * 2);
  unsigned short* W1rT = (unsigned short*)(ws + off); off += alignup((size_t)128 * 1152 * 2);
  unsigned short* B2pad = (unsigned short*)(ws + off); off += alignup((size_t)128 * 128 * 2);
  float* h2 = (float*)(ws + off);        off += alignup((size_t)NNODES * 18 * 4);
  size_t base = off;

  // pick smallest chunk count whose M9 buffer (1024 cols) fits
  int NCH = 0;
  for (int cand = 1; cand <= 16; cand <<= 1) {
    size_t ch = ((size_t)NNODES + cand - 1) / cand;
    if (base + alignup(ch * 1024 * 2) <= ws_size) { NCH = cand; break; }
  }
  if (NCH == 0) {
    fill_sentinel<<<(out_size + 255) / 256, blk, 0, stream>>>((float*)d_out, out_size, -777.0f);
    return;
  }
  unsigned short* M9 = (unsigned short*)(ws + base);
  const int CH = (NNODES + NCH - 1) / NCH;

  hipMemsetAsync(cnt_dt, 0, (size_t)NSEG * 4, stream);

  // ---- weight repacks ----
  build_Bt<<<(128 * 256 + 255) / 256, blk, 0, stream>>>(Wu, WuT, 256, 128);
  build_Bt<<<(128 * 512 + 255) / 256, blk, 0, stream>>>(Wf, WfT, 512, 128);
  build_Bt<<<(128 * 128 + 255) / 256, blk, 0, stream>>>(Wi, WiT, 128, 128);
  build_Bt<<<(128 * 64 + 255) / 256, blk, 0, stream>>>(Wc, WcT, 64, 128);
  build_Bt<<<(128 * 64 + 255) / 256, blk, 0, stream>>>(Wh, WhT, 64, 128);
  build_W1rT<<<(128 * 1152 + 255) / 256, blk, 0, stream>>>(W1, root1, W1rT);
  build_B2pad<<<(128 * 128 + 255) / 256, blk, 0, stream>>>(W2, root2, B2pad);

  // ---- projections -> x_all (bf16) ----
  { dim3 g(1, (NU + 127) / 128);
    mfma_gemm<true, true, false><<<g, blk, 0, stream>>>(x_user, WuT, 256, bu, (void*)x_all, 128, 128, NU, 128, 256); }
  { dim3 g(1, (NFOOD + 127) / 128);
    mfma_gemm<true, true, false><<<g, blk, 0, stream>>>(x_food, WfT, 512, bfo, (void*)(x_all + (size_t)NU * 128), 128, 128, NFOOD, 128, 512); }
  { dim3 g(1, (NING + 127) / 128);
    mfma_gemm<true, true, false><<<g, blk, 0, stream>>>(x_ing, WiT, 128, bi, (void*)(x_all + (size_t)(NU + NFOOD) * 128), 128, 128, NING, 128, 128); }
  { dim3 g(1, (NCAT + 127) / 128);
    mfma_gemm<true, true, false><<<g, blk, 0, stream>>>(x_cat, WcT, 64, bc, (void*)(x_all + (size_t)(NU + NFOOD + NING) * 128), 128, 128, NCAT, 128, 64); }
  { dim3 g(1, (NHAB + 127) / 128);
    mfma_gemm<true, true, false><<<g, blk, 0, stream>>>(x_hab, WhT, 64, bh, (void*)(x_all + (size_t)(NU + NFOOD + NING + NCAT) * 128), 128, 128, NHAB, 128, 64); }

  // ---- (dst,rel)-keyed CSR build (XCD-partitioned, 3-level scan) ----
  count_dt_xcd<<<2048, blk, 0, stream>>>(ei, et, cnt_dt);
  scan_block<<<NB_A, SCAN_B, 0, stream>>>(cnt_dt, rp2, bsumA, NSEG);
  scan_block<<<NB_B, SCAN_B, 0, stream>>>(bsumA, bsumAs, bsumB, NB_A);
  scan_top<<<1, 512, 0, stream>>>(bsumB, bofsB, NB_B);
  scan_apply3<<<NB_A, SCAN_B, 0, stream>>>(rp2, bsumAs, bofsB, slot, NSEG);
  scatter_edges_xcd<<<2048, blk, 0, stream>>>(ei, et, slot, packed);

  // ---- layer 1: per dst-chunk, single-pass gather + K=1152 GEMM -> x1 ----
  for (int c = 0; c < NCH; ++c) {
    int d0 = c * CH;
    int d1 = (d0 + CH < NNODES) ? d0 + CH : NNODES;
    int Mc = d1 - d0;
    gather_means8<<<2048, blk, 0, stream>>>(rp2, packed, (const unsigned*)x_all,
                                            (unsigned*)M9, d0, d1);
    dim3 g(1, (Mc + 127) / 128);
    l1_gemm<<<g, blk, 0, stream>>>(M9, x_all, W1rT, b1, x1, d0, Mc);
  }

  // ---- layer 2: h2 = x1 @ B2pad (store 18 cols) ----
  { dim3 g(1, (NNODES + 127) / 128);
    mfma_gemm<false, false, false><<<g, blk, 0, stream>>>(x1, B2pad, 128, nullptr, (void*)h2, 18, 18, NNODES, 128, 128); }

  fused_out<<<(NNODES * 4 + 255) / 256, blk, 0, stream>>>(rp2, packed, h2, b2, (float*)d_out);
}

// Round 11
// 543.493 us; speedup vs baseline: 1.6580x; 1.0189x over previous
//
#include <hip/hip_runtime.h>
#include <hip/hip_bf16.h>
#include <math.h>

#define NU 50000
#define NFOOD 30000
#define NING 20000
#define NCAT 5000
#define NHAB 10000
#define NNODES 115000
#define NCHUNK 14375   // NNODES/8 (XCD dst partition)
#define NREL 8
#define NSEG (NNODES * NREL)   // 920000
#define NEDGE 1500000
#define SCAN_B 256

typedef __attribute__((ext_vector_type(8))) short short8;
typedef __attribute__((ext_vector_type(4))) float f32x4;

static inline size_t alignup(size_t x) { return (x + 255) & ~(size_t)255; }

__device__ inline float bf16_bits_to_f32(unsigned short u) {
  return __uint_as_float(((unsigned)u) << 16);
}
__device__ inline unsigned short f32_to_bf16_bits(float f) {
  unsigned u = __float_as_uint(f);
  unsigned r = u + 0x7fffu + ((u >> 16) & 1u);
  return (unsigned short)(r >> 16);
}

// ================= MFMA bf16 GEMM (generic) ========================================
template <bool A_F32, bool OUT_BF16, bool RELU_OUT>
__global__ __launch_bounds__(256) void mfma_gemm(
    const void* __restrict__ Ain, const unsigned short* __restrict__ Bt, int ldB,
    const float* __restrict__ bias, void* __restrict__ Cv, int ldC, int Nstore,
    int M, int N, int K) {
  __shared__ char As[128 * 128];
  __shared__ char Bs[128 * 128];
  const int tid = threadIdx.x;
  const int lane = tid & 63;
  const int wv = tid >> 6;
  const int bm = blockIdx.y * 128;
  const int bn = blockIdx.x * 128;
  f32x4 acc[2][8] = {};

  for (int k0 = 0; k0 < K; k0 += 64) {
    if (A_F32) {
      const float* A = (const float*)Ain;
#pragma unroll
      for (int it = 0; it < 4; ++it) {
        int u = it * 256 + tid;
        int m = u >> 3, c = u & 7;
        int mg = bm + m; if (mg >= M) mg = M - 1;
        const float4* src = (const float4*)(A + (size_t)mg * K + k0 + c * 8);
        float4 lo4 = src[0], hi4 = src[1];
        unsigned q0 = f32_to_bf16_bits(lo4.x) | ((unsigned)f32_to_bf16_bits(lo4.y) << 16);
        unsigned q1 = f32_to_bf16_bits(lo4.z) | ((unsigned)f32_to_bf16_bits(lo4.w) << 16);
        unsigned q2 = f32_to_bf16_bits(hi4.x) | ((unsigned)f32_to_bf16_bits(hi4.y) << 16);
        unsigned q3 = f32_to_bf16_bits(hi4.z) | ((unsigned)f32_to_bf16_bits(hi4.w) << 16);
        int off = m * 128 + ((c * 16) ^ ((m & 7) << 4));
        *(int4*)(As + off) = make_int4(q0, q1, q2, q3);
      }
    } else {
      const unsigned short* A = (const unsigned short*)Ain;
#pragma unroll
      for (int it = 0; it < 4; ++it) {
        int u = it * 256 + tid;
        int m = u >> 3, c = u & 7;
        int mg = bm + m; if (mg >= M) mg = M - 1;
        int4 v = *(const int4*)((const char*)(A + (size_t)mg * K + k0) + c * 16);
        int off = m * 128 + ((c * 16) ^ ((m & 7) << 4));
        *(int4*)(As + off) = v;
      }
    }
#pragma unroll
    for (int it = 0; it < 4; ++it) {
      int u = it * 256 + tid;
      int n = u >> 3, c = u & 7;
      int4 v = *(const int4*)((const char*)(Bt + (size_t)(bn + n) * ldB + k0) + c * 16);
      int off = n * 128 + ((c * 16) ^ ((n & 7) << 4));
      *(int4*)(Bs + off) = v;
    }
    __syncthreads();
#pragma unroll
    for (int kk = 0; kk < 2; ++kk) {
      int kbyte = kk * 64 + ((lane >> 4) << 4);
      short8 af[2];
#pragma unroll
      for (int mi = 0; mi < 2; ++mi) {
        int m = wv * 32 + mi * 16 + (lane & 15);
        af[mi] = *(const short8*)(As + m * 128 + (kbyte ^ ((m & 7) << 4)));
      }
#pragma unroll
      for (int ni = 0; ni < 8; ++ni) {
        int n = ni * 16 + (lane & 15);
        short8 bf = *(const short8*)(Bs + n * 128 + (kbyte ^ ((n & 7) << 4)));
#pragma unroll
        for (int mi = 0; mi < 2; ++mi)
          acc[mi][ni] = __builtin_amdgcn_mfma_f32_16x16x32_bf16(af[mi], bf, acc[mi][ni], 0, 0, 0);
      }
    }
    __syncthreads();
  }
#pragma unroll
  for (int mi = 0; mi < 2; ++mi) {
#pragma unroll
    for (int r = 0; r < 4; ++r) {
      int row = bm + wv * 32 + mi * 16 + ((lane >> 4) << 2) + r;
      if (row < M) {
#pragma unroll
        for (int ni = 0; ni < 8; ++ni) {
          int col = bn + ni * 16 + (lane & 15);
          if (col < Nstore) {
            float v = acc[mi][ni][r] + (bias ? bias[col] : 0.f);
            if (RELU_OUT) v = fmaxf(v, 0.f);
            if (OUT_BF16)
              ((unsigned short*)Cv)[(size_t)row * ldC + col] = f32_to_bf16_bits(v);
            else
              ((float*)Cv)[(size_t)row * ldC + col] = v;
          }
        }
      }
    }
  }
}

// ================= layer-1 GEMM: A = [M9 (1024 cols) | x_all rows] =================
__global__ __launch_bounds__(256) void l1_gemm(
    const unsigned short* __restrict__ M9, const unsigned short* __restrict__ xall,
    const unsigned short* __restrict__ W1rT, const float* __restrict__ b1,
    unsigned short* __restrict__ x1, int d0, int Mc) {
  __shared__ char As[128 * 128];
  __shared__ char Bs[128 * 128];
  const int tid = threadIdx.x;
  const int lane = tid & 63;
  const int wv = tid >> 6;
  const int bm = blockIdx.y * 128;
  f32x4 acc[2][8] = {};

  for (int k0 = 0; k0 < 1152; k0 += 64) {
#pragma unroll
    for (int it = 0; it < 4; ++it) {
      int u = it * 256 + tid;
      int m = u >> 3, c = u & 7;
      int mg = bm + m; if (mg >= Mc) mg = Mc - 1;
      const char* src;
      if (k0 < 1024) src = (const char*)(M9 + (size_t)mg * 1024 + k0) + c * 16;
      else src = (const char*)(xall + (size_t)(d0 + mg) * 128 + (k0 - 1024)) + c * 16;
      int4 v = *(const int4*)src;
      int off = m * 128 + ((c * 16) ^ ((m & 7) << 4));
      *(int4*)(As + off) = v;
    }
#pragma unroll
    for (int it = 0; it < 4; ++it) {
      int u = it * 256 + tid;
      int n = u >> 3, c = u & 7;
      int4 v = *(const int4*)((const char*)(W1rT + (size_t)n * 1152 + k0) + c * 16);
      int off = n * 128 + ((c * 16) ^ ((n & 7) << 4));
      *(int4*)(Bs + off) = v;
    }
    __syncthreads();
#pragma unroll
    for (int kk = 0; kk < 2; ++kk) {
      int kbyte = kk * 64 + ((lane >> 4) << 4);
      short8 af[2];
#pragma unroll
      for (int mi = 0; mi < 2; ++mi) {
        int m = wv * 32 + mi * 16 + (lane & 15);
        af[mi] = *(const short8*)(As + m * 128 + (kbyte ^ ((m & 7) << 4)));
      }
#pragma unroll
      for (int ni = 0; ni < 8; ++ni) {
        int n = ni * 16 + (lane & 15);
        short8 bf = *(const short8*)(Bs + n * 128 + (kbyte ^ ((n & 7) << 4)));
#pragma unroll
        for (int mi = 0; mi < 2; ++mi)
          acc[mi][ni] = __builtin_amdgcn_mfma_f32_16x16x32_bf16(af[mi], bf, acc[mi][ni], 0, 0, 0);
      }
    }
    __syncthreads();
  }
#pragma unroll
  for (int mi = 0; mi < 2; ++mi) {
#pragma unroll
    for (int r = 0; r < 4; ++r) {
      int row = bm + wv * 32 + mi * 16 + ((lane >> 4) << 2) + r;
      if (row < Mc) {
#pragma unroll
        for (int ni = 0; ni < 8; ++ni) {
          int col = ni * 16 + (lane & 15);
          float v = fmaxf(acc[mi][ni][r] + b1[col], 0.f);
          x1[(size_t)(d0 + row) * 128 + col] = f32_to_bf16_bits(v);
        }
      }
    }
  }
}

// ================= weight repacks ==================================================
__global__ void build_Bt(const float* __restrict__ W, unsigned short* __restrict__ Wt,
                         int K, int N) {
  int idx = blockIdx.x * blockDim.x + threadIdx.x;
  if (idx >= N * K) return;
  int n = idx / K, k = idx - n * K;
  Wt[idx] = f32_to_bf16_bits(W[(size_t)k * N + n]);
}

__global__ void build_W1rT(const float* __restrict__ W1, const float* __restrict__ root1,
                           unsigned short* __restrict__ Wt) {
  int idx = blockIdx.x * blockDim.x + threadIdx.x;
  if (idx >= 128 * 1152) return;
  int f = idx / 1152, c = idx - f * 1152;
  float v;
  if (c < 1024) { int t = c >> 7, k = c & 127; v = W1[((size_t)t * 128 + k) * 128 + f]; }
  else { int k = c - 1024; v = root1[(size_t)k * 128 + f]; }
  Wt[idx] = f32_to_bf16_bits(v);
}

__global__ void build_B2pad(const float* __restrict__ W2, const float* __restrict__ root2,
                            unsigned short* __restrict__ Bt) {
  int idx = blockIdx.x * blockDim.x + threadIdx.x;
  if (idx >= 128 * 128) return;
  int n = idx >> 7, k = idx & 127;
  float v = 0.f;
  if (n < 16) v = W2[((size_t)(n >> 1) * 128 + k) * 2 + (n & 1)];
  else if (n < 18) v = root2[(size_t)k * 2 + (n - 16)];
  Bt[idx] = f32_to_bf16_bits(v);
}

// ========== CSR build keyed by (dst, rel), XCD-partitioned by dst chunk ===========
__global__ void count_dt_xcd(const int* __restrict__ ei, const int* __restrict__ et,
                             int* __restrict__ cnt_dt) {
  int cls = blockIdx.x & 7;
  unsigned lo = cls * NCHUNK, hi = lo + NCHUNK;
  int e = (blockIdx.x >> 3) * blockDim.x + threadIdx.x;
  int stride = (gridDim.x >> 3) * blockDim.x;
  for (; e < NEDGE; e += stride) {
    unsigned d = (unsigned)ei[NEDGE + e]; if (d >= NNODES) d = 0;
    if (d < lo || d >= hi) continue;
    unsigned t = (unsigned)et[e]; if (t >= NREL) t = 0;
    atomicAdd(cnt_dt + d * NREL + t, 1);
  }
}

__global__ void scan_block(const int* __restrict__ in, int* __restrict__ out,
                           int* __restrict__ bsum, int n) {
  __shared__ int s[SCAN_B];
  int i = blockIdx.x * SCAN_B + threadIdx.x;
  int x = (i < n) ? in[i] : 0;
  s[threadIdx.x] = x;
  __syncthreads();
  for (int d = 1; d < SCAN_B; d <<= 1) {
    int v = (threadIdx.x >= d) ? s[threadIdx.x - d] : 0;
    __syncthreads();
    s[threadIdx.x] += v;
    __syncthreads();
  }
  if (i < n) out[i] = s[threadIdx.x] - x;
  if (threadIdx.x == SCAN_B - 1) bsum[blockIdx.x] = s[threadIdx.x];
}

__global__ void scan_top(int* __restrict__ bsum, int* __restrict__ bofs, int nb) {
  __shared__ int s[512];
  int x = (threadIdx.x < nb) ? bsum[threadIdx.x] : 0;
  s[threadIdx.x] = x;
  __syncthreads();
  for (int d = 1; d < 512; d <<= 1) {
    int v = (threadIdx.x >= d) ? s[threadIdx.x - d] : 0;
    __syncthreads();
    s[threadIdx.x] += v;
    __syncthreads();
  }
  if (threadIdx.x < nb) bofs[threadIdx.x] = s[threadIdx.x] - x;
}

__global__ void scan_apply3(int* __restrict__ rp2, const int* __restrict__ lvl1,
                            const int* __restrict__ lvl2, int* __restrict__ slot, int n) {
  int i = blockIdx.x * blockDim.x + threadIdx.x;
  if (i >= n) return;
  int v = rp2[i] + lvl1[i >> 8] + lvl2[i >> 16];
  rp2[i] = v;
  slot[i] = v;
}

__global__ void scatter_edges_xcd(const int* __restrict__ ei, const int* __restrict__ et,
                                  int* __restrict__ slot, unsigned* __restrict__ packed) {
  int cls = blockIdx.x & 7;
  unsigned lo = cls * NCHUNK, hi = lo + NCHUNK;
  int e = (blockIdx.x >> 3) * blockDim.x + threadIdx.x;
  int stride = (gridDim.x >> 3) * blockDim.x;
  for (; e < NEDGE; e += stride) {
    unsigned d = (unsigned)ei[NEDGE + e]; if (d >= NNODES) d = 0;
    if (d < lo || d >= hi) continue;
    unsigned s = (unsigned)ei[e];  if (s >= NNODES) s = 0;
    unsigned t = (unsigned)et[e];  if (t >= NREL)  t = 0;
    int pos = atomicAdd(slot + d * NREL + t, 1);
    packed[pos] = s;
  }
}

// ===== layer-1 gather-means: ROUND-BASED walk (8 gathers in flight per round) ======
// M9[d-d0] = 8 x 128 relation means (1024 cols bf16). All branch predicates are
// wave-uniform (segment bounds), accumulators statically indexed.
__global__ __launch_bounds__(256) void gather_rounds(
    const int* __restrict__ rp2, const unsigned* __restrict__ packed,
    const unsigned* __restrict__ xu, unsigned* __restrict__ M9, int d0, int d1) {
  int lane = threadIdx.x & 63;
  int wid = (blockIdx.x * blockDim.x + threadIdx.x) >> 6;
  int nw = (gridDim.x * blockDim.x) >> 6;
  for (int d = d0 + wid; d < d1; d += nw) {
    int base_i = d * NREL;
    int b[9];
#pragma unroll
    for (int q = 0; q < 9; ++q)
      b[q] = (base_i + q == NSEG) ? NEDGE : rp2[base_i + q];
    int len[8];
    int mx = 0;
#pragma unroll
    for (int q = 0; q < 8; ++q) { len[q] = b[q + 1] - b[q]; mx = len[q] > mx ? len[q] : mx; }
    float a0[8], a1[8];
#pragma unroll
    for (int q = 0; q < 8; ++q) { a0[q] = 0.f; a1[q] = 0.f; }
    for (int r = 0; r < mx; ++r) {
#pragma unroll
      for (int q = 0; q < 8; ++q) {
        if (r < len[q]) {   // wave-uniform predicate
          unsigned u = xu[(size_t)packed[b[q] + r] * 64 + lane];
          a0[q] += bf16_bits_to_f32((unsigned short)(u & 0xffffu));
          a1[q] += bf16_bits_to_f32((unsigned short)(u >> 16));
        }
      }
    }
    unsigned* rowp = M9 + (size_t)(d - d0) * 512;
#pragma unroll
    for (int q = 0; q < 8; ++q) {
      float w = 1.0f / (float)(len[q] > 0 ? len[q] : 1);
      rowp[q * 64 + lane] = f32_to_bf16_bits(a0[q] * w) |
                            ((unsigned)f32_to_bf16_bits(a1[q] * w) << 16);
    }
  }
}

// ===== layer-2 aggregation + log_softmax (4 lanes/dst; lane owns 2 relations) ======
__global__ void fused_out(const int* __restrict__ rp2, const unsigned* __restrict__ packed,
                          const float* __restrict__ h2, const float* __restrict__ b2,
                          float* __restrict__ out) {
  int gt = blockIdx.x * blockDim.x + threadIdx.x;
  int d = gt >> 2;
  int l4 = gt & 3;
  if (d >= NNODES) return;
  float z0 = 0.f, z1 = 0.f;
#pragma unroll
  for (int k = 0; k < 2; ++k) {
    int t = l4 * 2 + k;
    int i = d * NREL + t;
    int beg = rp2[i];
    int end = (i == NSEG - 1) ? NEDGE : rp2[i + 1];
    float s0 = 0.f, s1 = 0.f;
    for (int e = beg; e < end; ++e) {
      unsigned s = packed[e];
      s0 += h2[(size_t)s * 18 + t * 2];
      s1 += h2[(size_t)s * 18 + t * 2 + 1];
    }
    int c = end - beg;
    float w = 1.0f / (float)(c > 0 ? c : 1);
    z0 += s0 * w;
    z1 += s1 * w;
  }
  z0 += __shfl_xor(z0, 1, 4); z0 += __shfl_xor(z0, 2, 4);
  z1 += __shfl_xor(z1, 1, 4); z1 += __shfl_xor(z1, 2, 4);
  if (l4 == 0) {
    z0 += h2[(size_t)d * 18 + 16] + b2[0];
    z1 += h2[(size_t)d * 18 + 17] + b2[1];
    float m = fmaxf(z0, z1);
    float l = m + logf(expf(z0 - m) + expf(z1 - m));
    out[(size_t)d * 2 + 0] = z0 - l;
    out[(size_t)d * 2 + 1] = z1 - l;
  }
}

__global__ void fill_sentinel(float* __restrict__ out, int n, float v) {
  int i = blockIdx.x * blockDim.x + threadIdx.x;
  if (i < n) out[i] = v;
}

// ===================================================================================
extern "C" void kernel_launch(void* const* d_in, const int* in_sizes, int n_in,
                              void* d_out, int out_size, void* d_ws, size_t ws_size,
                              hipStream_t stream) {
  const float* x_user = (const float*)d_in[0];
  const float* x_food = (const float*)d_in[1];
  const float* x_ing  = (const float*)d_in[2];
  const float* x_cat  = (const float*)d_in[3];
  const float* x_hab  = (const float*)d_in[4];
  const float* Wu = (const float*)d_in[5];  const float* bu  = (const float*)d_in[6];
  const float* Wf = (const float*)d_in[7];  const float* bfo = (const float*)d_in[8];
  const float* Wi = (const float*)d_in[9];  const float* bi  = (const float*)d_in[10];
  const float* Wc = (const float*)d_in[11]; const float* bc  = (const float*)d_in[12];
  const float* Wh = (const float*)d_in[13]; const float* bh  = (const float*)d_in[14];
  const float* W1 = (const float*)d_in[15]; const float* root1 = (const float*)d_in[16];
  const float* b1 = (const float*)d_in[17];
  const float* W2 = (const float*)d_in[18]; const float* root2 = (const float*)d_in[19];
  const float* b2 = (const float*)d_in[20];
  const int* ei = (const int*)d_in[21];
  const int* et = (const int*)d_in[22];
  (void)in_sizes; (void)n_in;

  dim3 blk(256);
  const int NB_A = (NSEG + SCAN_B - 1) / SCAN_B;   // 3594
  const int NB_B = (NB_A + SCAN_B - 1) / SCAN_B;   // 15

  // ---- base layout (~86 MB) ----
  char* ws = (char*)d_ws;
  size_t off = 0;
  unsigned short* x_all = (unsigned short*)(ws + off); off += alignup((size_t)NNODES * 128 * 2);
  unsigned short* x1    = (unsigned short*)(ws + off); off += alignup((size_t)NNODES * 128 * 2);
  int* cnt_dt = (int*)(ws + off);        off += alignup((size_t)NSEG * 4);
  int* rp2 = (int*)(ws + off);           off += alignup((size_t)NSEG * 4);
  int* slot = (int*)(ws + off);          off += alignup((size_t)NSEG * 4);
  unsigned* packed = (unsigned*)(ws + off); off += alignup((size_t)NEDGE * 4);
  int* bsumA = (int*)(ws + off);         off += alignup((size_t)4096 * 4);
  int* bsumAs = (int*)(ws + off);        off += alignup((size_t)4096 * 4);
  int* bsumB = (int*)(ws + off);         off += alignup((size_t)64 * 4);
  int* bofsB = (int*)(ws + off);         off += alignup((size_t)64 * 4);
  unsigned short* WuT = (unsigned short*)(ws + off); off += alignup((size_t)128 * 256 * 2);
  unsigned short* WfT = (unsigned short*)(ws + off); off += alignup((size_t)128 * 512 * 2);
  unsigned short* WiT = (unsigned short*)(ws + off); off += alignup((size_t)128 * 128 * 2);
  unsigned short* WcT = (unsigned short*)(ws + off); off += alignup((size_t)128 * 64 * 2);
  unsigned short* WhT = (unsigned short*)(ws + off); off += alignup((size_t)128 * 64 * 2);
  unsigned short* W1rT = (unsigned short*)(ws + off); off += alignup((size_t)128 * 1152 * 2);
  unsigned short* B2pad = (unsigned short*)(ws + off); off += alignup((size_t)128 * 128 * 2);
  float* h2 = (float*)(ws + off);        off += alignup((size_t)NNODES * 18 * 4);
  size_t base = off;

  // pick smallest chunk count whose M9 buffer (1024 cols) fits
  int NCH = 0;
  for (int cand = 1; cand <= 16; cand <<= 1) {
    size_t ch = ((size_t)NNODES + cand - 1) / cand;
    if (base + alignup(ch * 1024 * 2) <= ws_size) { NCH = cand; break; }
  }
  if (NCH == 0) {
    fill_sentinel<<<(out_size + 255) / 256, blk, 0, stream>>>((float*)d_out, out_size, -777.0f);
    return;
  }
  unsigned short* M9 = (unsigned short*)(ws + base);
  const int CH = (NNODES + NCH - 1) / NCH;

  hipMemsetAsync(cnt_dt, 0, (size_t)NSEG * 4, stream);

  // ---- weight repacks ----
  build_Bt<<<(128 * 256 + 255) / 256, blk, 0, stream>>>(Wu, WuT, 256, 128);
  build_Bt<<<(128 * 512 + 255) / 256, blk, 0, stream>>>(Wf, WfT, 512, 128);
  build_Bt<<<(128 * 128 + 255) / 256, blk, 0, stream>>>(Wi, WiT, 128, 128);
  build_Bt<<<(128 * 64 + 255) / 256, blk, 0, stream>>>(Wc, WcT, 64, 128);
  build_Bt<<<(128 * 64 + 255) / 256, blk, 0, stream>>>(Wh, WhT, 64, 128);
  build_W1rT<<<(128 * 1152 + 255) / 256, blk, 0, stream>>>(W1, root1, W1rT);
  build_B2pad<<<(128 * 128 + 255) / 256, blk, 0, stream>>>(W2, root2, B2pad);

  // ---- projections -> x_all (bf16) ----
  { dim3 g(1, (NU + 127) / 128);
    mfma_gemm<true, true, false><<<g, blk, 0, stream>>>(x_user, WuT, 256, bu, (void*)x_all, 128, 128, NU, 128, 256); }
  { dim3 g(1, (NFOOD + 127) / 128);
    mfma_gemm<true, true, false><<<g, blk, 0, stream>>>(x_food, WfT, 512, bfo, (void*)(x_all + (size_t)NU * 128), 128, 128, NFOOD, 128, 512); }
  { dim3 g(1, (NING + 127) / 128);
    mfma_gemm<true, true, false><<<g, blk, 0, stream>>>(x_ing, WiT, 128, bi, (void*)(x_all + (size_t)(NU + NFOOD) * 128), 128, 128, NING, 128, 128); }
  { dim3 g(1, (NCAT + 127) / 128);
    mfma_gemm<true, true, false><<<g, blk, 0, stream>>>(x_cat, WcT, 64, bc, (void*)(x_all + (size_t)(NU + NFOOD + NING) * 128), 128, 128, NCAT, 128, 64); }
  { dim3 g(1, (NHAB + 127) / 128);
    mfma_gemm<true, true, false><<<g, blk, 0, stream>>>(x_hab, WhT, 64, bh, (void*)(x_all + (size_t)(NU + NFOOD + NING + NCAT) * 128), 128, 128, NHAB, 128, 64); }

  // ---- (dst,rel)-keyed CSR build (XCD-partitioned, 3-level scan) ----
  count_dt_xcd<<<2048, blk, 0, stream>>>(ei, et, cnt_dt);
  scan_block<<<NB_A, SCAN_B, 0, stream>>>(cnt_dt, rp2, bsumA, NSEG);
  scan_block<<<NB_B, SCAN_B, 0, stream>>>(bsumA, bsumAs, bsumB, NB_A);
  scan_top<<<1, 512, 0, stream>>>(bsumB, bofsB, NB_B);
  scan_apply3<<<NB_A, SCAN_B, 0, stream>>>(rp2, bsumAs, bofsB, slot, NSEG);
  scatter_edges_xcd<<<2048, blk, 0, stream>>>(ei, et, slot, packed);

  // ---- layer 1: per dst-chunk, round-based gather + K=1152 GEMM -> x1 ----
  for (int c = 0; c < NCH; ++c) {
    int d0 = c * CH;
    int d1 = (d0 + CH < NNODES) ? d0 + CH : NNODES;
    int Mc = d1 - d0;
    gather_rounds<<<2048, blk, 0, stream>>>(rp2, packed, (const unsigned*)x_all,
                                            (unsigned*)M9, d0, d1);
    dim3 g(1, (Mc + 127) / 128);
    l1_gemm<<<g, blk, 0, stream>>>(M9, x_all, W1rT, b1, x1, d0, Mc);
  }

  // ---- layer 2: h2 = x1 @ B2pad (store 18 cols) ----
  { dim3 g(1, (NNODES + 127) / 128);
    mfma_gemm<false, false, false><<<g, blk, 0, stream>>>(x1, B2pad, 128, nullptr, (void*)h2, 18, 18, NNODES, 128, 128); }

  fused_out<<<(NNODES * 4 + 255) / 256, blk, 0, stream>>>(rp2, packed, h2, b2, (float*)d_out);
}